// Round 8
// baseline (7228.174 us; speedup 1.0000x reference)
//
#include <hip/hip_runtime.h>
#include <math.h>

#define B_  16
#define TE_ 400
#define TD_ 64
#define E_  256
#define H_  512
#define H2_ 1024
#define V_  32000

typedef __attribute__((ext_vector_type(4))) float f32x4;
typedef __attribute__((ext_vector_type(8))) short s16x8;
typedef __attribute__((ext_vector_type(8))) unsigned short u16x8;
typedef __attribute__((ext_vector_type(4))) unsigned short u16x4;

__device__ __forceinline__ float bf2f(unsigned short u){
  union { unsigned int i; float f; } v; v.i = ((unsigned int)u) << 16; return v.f;
}
__device__ __forceinline__ unsigned short f2bf(float f){
  union { float f; unsigned int i; } v; v.f = f;
  return (unsigned short)((v.i + 0x7fffu + ((v.i >> 16) & 1u)) >> 16);
}
__device__ __forceinline__ float sigmoidf_(float x){ return 1.f/(1.f + expf(-x)); }

__device__ __forceinline__ void gl_lds16(const void* gsrc, void* ldst){
  __builtin_amdgcn_global_load_lds(
      (const __attribute__((address_space(1))) unsigned int*)gsrc,
      (__attribute__((address_space(3))) unsigned int*)ldst, 16, 0, 0);
}
__device__ __forceinline__ void issue4(const char* gsrc, char* ldst, int l){
  #pragma unroll
  for (int q = 0; q < 4; ++q)
    gl_lds16(gsrc + q*1024 + (size_t)l*16, ldst + q*1024);
}

// barrier lines over 8 x 16KB pages; one-shot instance per (phase,step)
__device__ __forceinline__ void d_arrive(unsigned* bars, int inst){
  __threadfence();
  __hip_atomic_fetch_add(bars + (blockIdx.x & 7u)*4096 + inst*16, 1u, __ATOMIC_RELAXED, __HIP_MEMORY_SCOPE_AGENT);
}
__device__ __forceinline__ void d_poll(unsigned* bars, int inst, unsigned tgt){
  int it = 0;
  for(;;){
    unsigned s = 0;
    #pragma unroll
    for (int k = 0; k < 8; ++k)
      s += __hip_atomic_load(bars + k*4096 + inst*16, __ATOMIC_RELAXED, __HIP_MEMORY_SCOPE_AGENT);
    if (s >= tgt) break;
    if (it < 6) __builtin_amdgcn_s_sleep(1);
    else if (it < 24) __builtin_amdgcn_s_sleep(4);
    else __builtin_amdgcn_s_sleep(16);
    ++it;
  }
  __threadfence();
}

// ---------------- init ----------------
__global__ void k_init(unsigned* bars, float* ctxn, float* psumT){
  int gid = blockIdx.x*256 + threadIdx.x;
  if (gid < 99328) bars[gid] = 0u;
  if (gid < 32768) ctxn[gid] = 0.f;
  if (gid < 32) psumT[gid] = 0.f;
}

// ---------------- embedding gather ----------------
__global__ void k_gather(const float* __restrict__ emb, const int* __restrict__ idx,
                         unsigned short* __restrict__ out, int T){
  int wv = threadIdx.x >> 6, l = threadIdx.x & 63;
  int row = blockIdx.x*4 + wv;
  if (row >= T*B_) return;
  int t = row >> 4, b = row & 15;
  int tok = idx[b*T + t];
  float4 v = *(const float4*)(emb + (size_t)tok*E_ + l*4);
  u16x4 o; o[0]=f2bf(v.x); o[1]=f2bf(v.y); o[2]=f2bf(v.z); o[3]=f2bf(v.w);
  *(u16x4*)(out + (size_t)row*E_ + l*4) = o;
}

// ---------------- prep encoder weights: gate-grouped [dir][2048][768] ----------------
__global__ void k_prep_enc(const float* __restrict__ Wih_f, const float* __restrict__ Whh_f,
                           const float* __restrict__ Wih_b, const float* __restrict__ Whh_b,
                           unsigned short* __restrict__ Wenc){
  int it = blockIdx.x*256 + threadIdx.x;
  int dir = it / (2048*96); int rem = it % (2048*96);
  int pr = rem / 96; int kc = rem % 96; int k0 = kc*8;
  int g = pr >> 6, r = pr & 63, gate = r >> 4, ul = r & 15;
  int orig = gate*H_ + g*16 + ul;
  const float* Wih = dir ? Wih_b : Wih_f;
  const float* Whh = dir ? Whh_b : Whh_f;
  u16x8 o;
  #pragma unroll
  for (int e = 0; e < 8; ++e){
    int k = k0 + e;
    float v = (k < E_) ? Wih[(size_t)orig*E_ + k] : Whh[(size_t)orig*H_ + (k - E_)];
    o[e] = f2bf(v);
  }
  *(u16x8*)(Wenc + ((size_t)dir*2048 + pr)*768 + k0) = o;
}

// ===== decoder resident-weight preps (unit-major: WG w owns units w*4..+3, all 4 gates) =====
// row r16 = gate*4 + uloc ; orig = gate*H2 + w*4 + uloc
// sub-block: [16 r][128 K] = row*256B + ((k8*16)^((row&7)<<4))
__device__ __forceinline__ void prep_rwhh_item(int it, const float* __restrict__ Whh_d,
                                               char* __restrict__ RW){
  int w = it >> 11; int rem = it & 2047;
  int sb = rem >> 8; int e = rem & 255;
  int row = e >> 4, k8 = e & 15;
  int orig = (row >> 2)*H2_ + w*4 + (row & 3);
  u16x8 o;
  #pragma unroll
  for (int e2 = 0; e2 < 8; ++e2)
    o[e2] = f2bf(Whh_d[(size_t)orig*H2_ + sb*128 + k8*8 + e2]);
  size_t off = (size_t)w*32768 + (size_t)sb*4096 + (size_t)(row*256 + ((k8*16) ^ ((row&7)<<4)));
  *(u16x8*)(RW + off) = o;
}
__device__ __forceinline__ void prep_rwctx_item(int it, const float* __restrict__ Wih_d,
                                                char* __restrict__ RC){
  int w = it >> 12; int rem = it & 4095;
  int sb = rem >> 8; int e = rem & 255;
  int row = e >> 4, k8 = e & 15;
  int orig = (row >> 2)*H2_ + w*4 + (row & 3);
  int col = 256 + sb*128 + k8*8;
  u16x8 o;
  #pragma unroll
  for (int e2 = 0; e2 < 8; ++e2)
    o[e2] = f2bf(Wih_d[(size_t)orig*2304 + col + e2]);
  size_t off = (size_t)w*65536 + (size_t)sb*4096 + (size_t)(row*256 + ((k8*16) ^ ((row&7)<<4)));
  *(u16x8*)(RC + off) = o;
}

// ---------------- prep WihEmbGrp [4096][256] (unit-major col layout) ----------------
__global__ void k_prep_wihemb(const float* __restrict__ Wih_d, unsigned short* __restrict__ Wemb){
  int it = blockIdx.x*256 + threadIdx.x;
  int p = it >> 5; int k0 = (it & 31)*8;
  int orig = ((p>>2)&3)*H2_ + (p>>4)*4 + (p&3);
  u16x8 o;
  #pragma unroll
  for (int e = 0; e < 8; ++e)
    o[e] = f2bf(Wih_d[(size_t)orig*2304 + k0 + e]);
  *(u16x8*)(Wemb + (size_t)p*256 + k0) = o;
}

// ---------------- zinit GEMM: [1024][4096] f32 = decemb @ WihEmbGrp^T + b_d ----------------
__global__ void __launch_bounds__(256, 2) k_zinit(
    const unsigned short* __restrict__ A,
    const unsigned short* __restrict__ Bw,
    const float* __restrict__ bd,
    float* __restrict__ Cz)
{
  __shared__ unsigned short Ab[128*72];
  __shared__ unsigned short Bt[128*72];
  int p = blockIdx.x;
  int mt = p >> 5, nt = p & 31;
  int m0 = mt*128, n0 = nt*128;
  int tid = threadIdx.x, wvv = tid>>6, l = tid&63;
  int wr = wvv>>1, wc = wvv&1;
  f32x4 zero4 = {0.f,0.f,0.f,0.f};
  f32x4 acc[4][4];
  #pragma unroll
  for (int a=0;a<4;++a){
    #pragma unroll
    for (int b=0;b<4;++b) acc[a][b] = zero4;
  }
  for (int k0 = 0; k0 < 256; k0 += 64){
    #pragma unroll
    for (int qq = 0; qq < 4; ++qq){
      int idx8 = (tid + qq*256)*8;
      int r = idx8 >> 6, k = idx8 & 63;
      *(u16x8*)(Ab + r*72 + k) = *(const u16x8*)(A + (size_t)(m0+r)*256 + k0 + k);
      *(u16x8*)(Bt + r*72 + k) = *(const u16x8*)(Bw + (size_t)(n0+r)*256 + k0 + k);
    }
    __syncthreads();
    #pragma unroll
    for (int ks = 0; ks < 2; ++ks){
      s16x8 af[4], bf[4];
      #pragma unroll
      for (int fi=0;fi<4;++fi)
        af[fi] = *(const s16x8*)(Ab + (wr*64+fi*16+(l&15))*72 + ks*32 + (l>>4)*8);
      #pragma unroll
      for (int fj=0;fj<4;++fj)
        bf[fj] = *(const s16x8*)(Bt + (wc*64+fj*16+(l&15))*72 + ks*32 + (l>>4)*8);
      #pragma unroll
      for (int fi=0;fi<4;++fi){
        #pragma unroll
        for (int fj=0;fj<4;++fj)
          acc[fi][fj] = __builtin_amdgcn_mfma_f32_16x16x32_bf16(af[fi], bf[fj], acc[fi][fj], 0,0,0);
      }
    }
    __syncthreads();
  }
  #pragma unroll
  for (int fj=0;fj<4;++fj){
    int col = n0 + wc*64 + fj*16 + (l&15);
    int orig = ((col>>2)&3)*H2_ + (col>>4)*4 + (col&3);
    float bias = bd[orig];
    #pragma unroll
    for (int fi=0;fi<4;++fi){
      #pragma unroll
      for (int j=0;j<4;++j){
        int row = m0 + wr*64 + fi*16 + (l>>4)*4 + j;
        Cz[(size_t)row*4096 + col] = acc[fi][fj][j] + bias;
      }
    }
  }
}

// ---------------- zx GEMM ----------------
__global__ void __launch_bounds__(256, 2) k_zx(
    const unsigned short* __restrict__ xs,
    const unsigned short* __restrict__ Wenc,
    const float* __restrict__ b_f, const float* __restrict__ b_b,
    unsigned short* __restrict__ zx)
{
  __shared__ unsigned short Ab[128*72];
  __shared__ unsigned short Bt[128*72];
  int pblk = blockIdx.x;
  int dir = pblk / 800; int rem = pblk % 800;
  int mt = rem >> 4, nt = rem & 15;
  int m0 = mt*128, n0 = nt*128;
  int tid = threadIdx.x, wvv = tid>>6, l = tid&63;
  int wr = wvv>>1, wc = wvv&1;
  f32x4 zero4 = {0.f,0.f,0.f,0.f};
  f32x4 acc[4][4];
  #pragma unroll
  for (int a=0;a<4;++a){
    #pragma unroll
    for (int b=0;b<4;++b) acc[a][b] = zero4;
  }
  for (int k0 = 0; k0 < 256; k0 += 64){
    #pragma unroll
    for (int qq = 0; qq < 4; ++qq){
      int idx8 = (tid + qq*256)*8;
      int r = idx8 >> 6, k = idx8 & 63;
      *(u16x8*)(Ab + r*72 + k) = *(const u16x8*)(xs + (size_t)(m0+r)*256 + k0 + k);
      *(u16x8*)(Bt + r*72 + k) = *(const u16x8*)(Wenc + ((size_t)dir*2048 + n0+r)*768 + k0 + k);
    }
    __syncthreads();
    #pragma unroll
    for (int ks = 0; ks < 2; ++ks){
      s16x8 af[4], bf[4];
      #pragma unroll
      for (int fi=0;fi<4;++fi)
        af[fi] = *(const s16x8*)(Ab + (wr*64+fi*16+(l&15))*72 + ks*32 + (l>>4)*8);
      #pragma unroll
      for (int fj=0;fj<4;++fj)
        bf[fj] = *(const s16x8*)(Bt + (wc*64+fj*16+(l&15))*72 + ks*32 + (l>>4)*8);
      #pragma unroll
      for (int fi=0;fi<4;++fi){
        #pragma unroll
        for (int fj=0;fj<4;++fj)
          acc[fi][fj] = __builtin_amdgcn_mfma_f32_16x16x32_bf16(af[fi], bf[fj], acc[fi][fj], 0,0,0);
      }
    }
    __syncthreads();
  }
  const float* bsrc = dir ? b_b : b_f;
  #pragma unroll
  for (int fj=0;fj<4;++fj){
    int col = n0 + wc*64 + fj*16 + (l&15);
    float bias = bsrc[((col>>4)&3)*512 + (col>>6)*16 + (col&15)];
    #pragma unroll
    for (int fi=0;fi<4;++fi){
      #pragma unroll
      for (int j=0;j<4;++j){
        int row = m0 + wr*64 + fi*16 + (l>>4)*4 + j;
        zx[((size_t)dir*6400 + row)*2048 + col] = f2bf(acc[fi][fj][j] + bias);
      }
    }
  }
}

// ---------------- Penc = enc_out @ W_ea^T (bf16) ----------------
__global__ void __launch_bounds__(256, 2) k_penc(
    const unsigned short* __restrict__ enc,
    const float* __restrict__ Wea,
    unsigned short* __restrict__ P)
{
  __shared__ unsigned short Ab[128*72];
  __shared__ unsigned short Bt[128*72];
  int p = blockIdx.x;
  int mt = p >> 3, nt = p & 7;
  int m0 = mt*128, n0 = nt*128;
  int tid = threadIdx.x, wvv = tid>>6, l = tid&63;
  int wr = wvv>>1, wc = wvv&1;
  f32x4 zero4 = {0.f,0.f,0.f,0.f};
  f32x4 acc[4][4];
  #pragma unroll
  for (int a=0;a<4;++a){
    #pragma unroll
    for (int b=0;b<4;++b) acc[a][b] = zero4;
  }
  for (int k0 = 0; k0 < 1024; k0 += 64){
    #pragma unroll
    for (int qq = 0; qq < 4; ++qq){
      int idx8 = (tid + qq*256)*8;
      int r = idx8 >> 6, k = idx8 & 63;
      *(u16x8*)(Ab + r*72 + k) = *(const u16x8*)(enc + (size_t)(m0+r)*1024 + k0 + k);
    }
    #pragma unroll
    for (int qq = 0; qq < 4; ++qq){
      int idx8 = (tid + qq*256)*8;
      int r = idx8 >> 6, k = idx8 & 63;
      const float* src = Wea + (size_t)(n0+r)*1024 + k0 + k;
      float4 v0 = *(const float4*)src;
      float4 v1 = *(const float4*)(src+4);
      u16x8 o;
      o[0]=f2bf(v0.x); o[1]=f2bf(v0.y); o[2]=f2bf(v0.z); o[3]=f2bf(v0.w);
      o[4]=f2bf(v1.x); o[5]=f2bf(v1.y); o[6]=f2bf(v1.z); o[7]=f2bf(v1.w);
      *(u16x8*)(Bt + r*72 + k) = o;
    }
    __syncthreads();
    #pragma unroll
    for (int ks = 0; ks < 2; ++ks){
      s16x8 af[4], bf[4];
      #pragma unroll
      for (int fi=0;fi<4;++fi)
        af[fi] = *(const s16x8*)(Ab + (wr*64+fi*16+(l&15))*72 + ks*32 + (l>>4)*8);
      #pragma unroll
      for (int fj=0;fj<4;++fj)
        bf[fj] = *(const s16x8*)(Bt + (wc*64+fj*16+(l&15))*72 + ks*32 + (l>>4)*8);
      #pragma unroll
      for (int fi=0;fi<4;++fi){
        #pragma unroll
        for (int fj=0;fj<4;++fj)
          acc[fi][fj] = __builtin_amdgcn_mfma_f32_16x16x32_bf16(af[fi], bf[fj], acc[fi][fj], 0,0,0);
      }
    }
    __syncthreads();
  }
  #pragma unroll
  for (int fj=0;fj<4;++fj){
    int col = n0 + wc*64 + fj*16 + (l&15);
    #pragma unroll
    for (int fi=0;fi<4;++fi){
      #pragma unroll
      for (int j=0;j<4;++j){
        int row = m0 + wr*64 + fi*16 + (l>>4)*4 + j;
        P[(size_t)row*1024 + col] = f2bf(acc[fi][fj][j]);
      }
    }
  }
}

// ---------------- persistent bi-LSTM encoder + prep WGs ----------------
__global__ void __launch_bounds__(256, 1) k_encoder(
    const unsigned short* __restrict__ zx,
    const unsigned short* __restrict__ Wenc,
    const float* __restrict__ h0, const float* __restrict__ c0,
    unsigned short* __restrict__ enc_out,
    unsigned short* __restrict__ hbuf,
    float* __restrict__ h0dec, float* __restrict__ c0dec,
    unsigned* __restrict__ bars,
    const float* __restrict__ Whh_d, const float* __restrict__ Wih_d,
    char* __restrict__ RWhhG, char* __restrict__ RWctxG)
{
  extern __shared__ char smem[];
  int tid = threadIdx.x;
  int w = blockIdx.x;
  if (w >= 64){
    int base = (w - 64)*256 + tid;
    for (int it = base; it < 524288; it += 36864) prep_rwhh_item(it, Whh_d, RWhhG);
    for (int it = base; it < 1048576; it += 36864) prep_rwctx_item(it, Wih_d, RWctxG);
    return;
  }
  unsigned short* Wt = (unsigned short*)smem;            // [64][520]
  unsigned short* At = Wt + 64*520;                      // [16][520]
  float* zl = (float*)(At + 16*520);                     // [4][16][16]
  int dir = w >> 5, g = w & 31;
  int wv = tid >> 6, l = tid & 63;
  unsigned* ebars = bars + 32768;
  {
    const unsigned short* Wsrc = Wenc + ((size_t)dir*2048 + g*64)*768 + 256;
    int r = tid >> 2, s = tid & 3;
    for (int c = 0; c < 16; ++c)
      *(u16x8*)(Wt + r*520 + s*128 + c*8) = *(const u16x8*)(Wsrc + (size_t)r*768 + s*128 + c*8);
  }
  int bb = tid >> 4, ul = tid & 15;
  float creg = c0[((size_t)dir*16 + bb)*H_ + g*16 + ul];
  int kchunk = (l >> 4) * 8;
  f32x4 zero4 = { 0.f, 0.f, 0.f, 0.f };
  {
    int r = tid >> 4, s = tid & 15;
    for (int e = 0; e < 32; ++e)
      At[r*520 + s*32 + e] = f2bf(h0[((size_t)dir*16 + r)*H_ + s*32 + e]);
  }
  int tg0 = dir ? (TE_-1) : 0;
  const unsigned short* zrow = zx + ((size_t)dir*6400 + (size_t)tg0*16 + (l>>4)*4)*2048 + g*64 + wv*16 + (l&15);
  f32x4 a0cur;
  a0cur[0]=bf2f(zrow[0]); a0cur[1]=bf2f(zrow[2048]); a0cur[2]=bf2f(zrow[4096]); a0cur[3]=bf2f(zrow[6144]);
  __syncthreads();
  for (int t = 0; t < TE_; ++t){
    int tg = dir ? (TE_-1 - t) : t;
    f32x4 acc0 = a0cur, acc1 = zero4;
    const unsigned short* brow = Wt + (wv*16 + (l&15))*520 + kchunk;
    const unsigned short* ap   = At + (l&15)*520 + kchunk;
    #pragma unroll
    for (int ks = 0; ks < 16; ++ks){
      s16x8 afr = *(const s16x8*)(ap + ks*32);
      s16x8 bfr = *(const s16x8*)(brow + ks*32);
      if (ks & 1) acc1 = __builtin_amdgcn_mfma_f32_16x16x32_bf16(afr, bfr, acc1, 0, 0, 0);
      else        acc0 = __builtin_amdgcn_mfma_f32_16x16x32_bf16(afr, bfr, acc0, 0, 0, 0);
    }
    f32x4 acc = acc0 + acc1;
    #pragma unroll
    for (int j = 0; j < 4; ++j)
      zl[wv*256 + ((l>>4)*4 + j)*16 + (l&15)] = acc[j];
    __syncthreads();
    float zi = zl[0*256 + bb*16 + ul];
    float zf = zl[1*256 + bb*16 + ul];
    float zg = zl[2*256 + bb*16 + ul];
    float zo = zl[3*256 + bb*16 + ul];
    float iv = sigmoidf_(zi), fv = sigmoidf_(zf), gv = tanhf(zg), ov = sigmoidf_(zo);
    float cc = fv*creg + iv*gv;
    float hh = ov * tanhf(cc);
    creg = cc;
    int u = g*16 + ul;
    unsigned short hb = f2bf(hh);
    hbuf[((size_t)dir*2 + ((t+1)&1))*(16*H_) + bb*H_ + u] = hb;
    enc_out[((size_t)bb*TE_ + tg)*H2_ + dir*H_ + u] = hb;
    if (t == TE_-1){
      h0dec[(size_t)bb*H2_ + dir*H_ + u] = hh;
      c0dec[(size_t)bb*H2_ + dir*H_ + u] = cc;
    }
    int inst = dir*400 + t;
    __syncthreads();
    if (tid == 0){
      __threadfence();
      __hip_atomic_fetch_add(ebars + (g&3)*16384 + inst*16, 1u, __ATOMIC_RELAXED, __HIP_MEMORY_SCOPE_AGENT);
    }
    if (t+1 < TE_){
      int tg2 = dir ? (TE_-2 - t) : (t+1);
      const unsigned short* zr2 = zx + ((size_t)dir*6400 + (size_t)tg2*16 + (l>>4)*4)*2048 + g*64 + wv*16 + (l&15);
      a0cur[0]=bf2f(zr2[0]); a0cur[1]=bf2f(zr2[2048]); a0cur[2]=bf2f(zr2[4096]); a0cur[3]=bf2f(zr2[6144]);
    }
    if (tid == 0){
      int it = 0;
      for(;;){
        unsigned s_ = 0;
        #pragma unroll
        for (int k2 = 0; k2 < 4; ++k2)
          s_ += __hip_atomic_load(ebars + k2*16384 + inst*16, __ATOMIC_RELAXED, __HIP_MEMORY_SCOPE_AGENT);
        if (s_ >= 32) break;
        if (it < 6) __builtin_amdgcn_s_sleep(1);
        else __builtin_amdgcn_s_sleep(4);
        ++it;
      }
      __threadfence();
    }
    __syncthreads();
    if (t+1 < TE_){
      int r = tid >> 4, s = tid & 15;
      const unsigned short* hsrc = hbuf + ((size_t)dir*2 + ((t+1)&1))*(16*H_) + r*H_ + s*32;
      for (int c = 0; c < 4; ++c)
        *(u16x8*)(At + r*520 + s*32 + c*8) = *(const u16x8*)(hsrc + c*8);
    }
    __syncthreads();
  }
}

__global__ void k_dec_init(const float* __restrict__ h0dec, unsigned short* __restrict__ hreg){
  int gid = blockIdx.x*256 + threadIdx.x;
  if (gid < 16384) hreg[gid] = f2bf(h0dec[gid]);
}

// ---------------- unified persistent decoder: 256 WGs, multi-role ----------------
// LDS: RW 32768 | PencL 51200 | WB 65536 | zl 8192 | epL 128 | accL 128 | dscL 256
#define OFF_PENC  32768
#define OFF_WB    83968
#define OFF_ZL    149504
#define OFF_EPL   157696
#define OFF_ACCL  157824
#define OFF_DSCL  157952
#define DEC_SMEM  158208

__global__ void __launch_bounds__(256, 1) k_decoder(
  const char* __restrict__ RWhhG,       // [256 w][8 sb][4KB]
  const char* __restrict__ RWctxG,      // [256 w][16 sb][4KB]
  const float* __restrict__ zinit,      // [1024][4096]
  const unsigned short* __restrict__ Penc,
  const unsigned short* __restrict__ enc_out,
  const float* __restrict__ W_da,       // f32 [1024][1024]
  const float* __restrict__ c0dec,
  unsigned short* __restrict__ hreg,    // [2][16][1024] bf16
  unsigned short* __restrict__ xbuf,    // [16][1024] bf16 ctx_d
  float* __restrict__ ctxn,             // [2][16][1024]
  float* __restrict__ psumT,            // [2][16]
  unsigned short* __restrict__ vbuf,    // [64][16][1024] bf16
  unsigned short* __restrict__ bufh,    // [64][16][1024] bf16
  unsigned short* __restrict__ Av,      // [1024][3072]
  float* __restrict__ outHC,
  unsigned* __restrict__ bars)
{
  extern __shared__ char smem[];
  char* RW = smem;
  unsigned short* PencL = (unsigned short*)(smem + OFF_PENC);
  char* WB = smem + OFF_WB;
  float* zl   = (float*)(smem + OFF_ZL);
  float* epL  = (float*)(smem + OFF_EPL);
  float* accL = (float*)(smem + OFF_ACCL);
  float* dscL = (float*)(smem + OFF_DSCL);

  int tid = threadIdx.x, w = blockIdx.x;
  int wv = tid >> 6, l = tid & 63;
  int b_att = w >> 4, tr = w & 15;
  bool isDec = ((w & 3) == 0);
  int qd = (w >> 2) & 3, b_dec = w >> 4;
  int swz = ((l&7)<<4);

  // load resident Whh slice + Penc slice
  {
    const float4* src = (const float4*)(RWhhG + (size_t)w*32768);
    float4* dst = (float4*)RW;
    for (int o = tid; o < 2048; o += 256) dst[o] = src[o];
    const float4* ps = (const float4*)(Penc + ((size_t)b_att*400 + tr*25)*1024);
    float4* pd = (float4*)PencL;
    for (int o = tid; o < 3200; o += 256) pd[o] = ps[o];
  }
  if (tid < 25) accL[tid] = 0.f;
  float creg = 0.f;
  if (tid < 64) creg = c0dec[(size_t)(tid>>2)*H2_ + w*4 + (tid&3)];
  __syncthreads();

  const char* gWB = RWctxG + (size_t)w*65536;
  char* myWB = WB + wv*16384;

  for (int i = 0; i < TD_; ++i){
    int p = i & 1;
    int instV = i*3, instX = i*3+1, instY = i*3+2;
    // zero next-step ctx accumulators
    if (w < 64){
      ctxn[(p^1)*16384 + w*256 + tid] = 0.f;
      if (w == 0 && tid < 16) psumT[(p^1)*16 + tid] = 0.f;
    }
    // issue Wctx stream for phase 2 (wave-private slots)
    issue4(gWB + (size_t)(2*wv+0)*4096, myWB + 0*4096, l);
    issue4(gWB + (size_t)(2*wv+1)*4096, myWB + 1*4096, l);
    issue4(gWB + (size_t)(8+2*wv)*4096, myWB + 2*4096, l);
    issue4(gWB + (size_t)(9+2*wv)*4096, myWB + 3*4096, l);
    // v-dots: v(i-1)[b][w*4+jl] = W_da[w*4+jl] . h_in(i)[b]
    if (i > 0){
      for (int bi = 0; bi < 4; ++bi){
        int b2 = wv*4 + bi;
        const unsigned short* hp = hreg + p*16384 + (size_t)b2*H2_ + l*16;
        u16x8 hv0 = *(const u16x8*)hp;
        u16x8 hv1 = *(const u16x8*)(hp + 8);
        float hfl[16];
        #pragma unroll
        for (int e = 0; e < 8; ++e){ hfl[e] = bf2f(hv0[e]); hfl[8+e] = bf2f(hv1[e]); }
        #pragma unroll
        for (int jl = 0; jl < 4; ++jl){
          const float* wr = W_da + (size_t)(w*4+jl)*H2_ + l*16;
          float4 w0 = *(const float4*)(wr);
          float4 w1 = *(const float4*)(wr+4);
          float4 w2 = *(const float4*)(wr+8);
          float4 w3 = *(const float4*)(wr+12);
          float s = hfl[0]*w0.x + hfl[1]*w0.y + hfl[2]*w0.z + hfl[3]*w0.w
                  + hfl[4]*w1.x + hfl[5]*w1.y + hfl[6]*w1.z + hfl[7]*w1.w
                  + hfl[8]*w2.x + hfl[9]*w2.y + hfl[10]*w2.z + hfl[11]*w2.w
                  + hfl[12]*w3.x + hfl[13]*w3.y + hfl[14]*w3.z + hfl[15]*w3.w;
          #pragma unroll
          for (int o = 1; o < 64; o <<= 1) s += __shfl_xor(s, o);
          if (l == 0) vbuf[((size_t)(i-1)*16 + b2)*H2_ + w*4 + jl] = f2bf(s);
        }
      }
    }
    if (tid == 0) d_arrive(bars, instV);
    // z phase-1: acc = zinit(w0) + Whh_slice @ h  (K-split by wave)
    f32x4 accz0, accz1;
    {
      f32x4 z4 = {0.f,0.f,0.f,0.f};
      accz1 = z4;
      if (wv == 0){
        const float* zsrc = zinit + ((size_t)i*16)*4096 + w*16 + (l&15);
        f32x4 a;
        a[0] = zsrc[(size_t)((l>>4)*4+0)*4096];
        a[1] = zsrc[(size_t)((l>>4)*4+1)*4096];
        a[2] = zsrc[(size_t)((l>>4)*4+2)*4096];
        a[3] = zsrc[(size_t)((l>>4)*4+3)*4096];
        accz0 = a;
      } else accz0 = z4;
    }
    {
      int kbase = wv*256;
      s16x8 af[8];
      #pragma unroll
      for (int ks = 0; ks < 8; ++ks)
        af[ks] = *(const s16x8*)(hreg + p*16384 + (size_t)(l&15)*H2_ + kbase + ks*32 + (l>>4)*8);
      #pragma unroll
      for (int ks = 0; ks < 8; ++ks){
        const char* sbL = RW + (size_t)(2*wv + (ks>>2))*4096;
        int k8 = (ks&3)*4 + (l>>4);
        s16x8 bfr = *(const s16x8*)(sbL + (l&15)*256 + ((k8*16) ^ swz));
        if (ks & 1) accz1 = __builtin_amdgcn_mfma_f32_16x16x32_bf16(af[ks], bfr, accz1, 0,0,0);
        else        accz0 = __builtin_amdgcn_mfma_f32_16x16x32_bf16(af[ks], bfr, accz0, 0,0,0);
      }
    }
    // enc-attention scores for 25 owned rows (b = b_att)
    {
      const unsigned short* hp = hreg + p*16384 + (size_t)b_att*H2_ + l*16;
      u16x8 hv0 = *(const u16x8*)hp;
      u16x8 hv1 = *(const u16x8*)(hp + 8);
      float hf[16];
      #pragma unroll
      for (int e = 0; e < 8; ++e){ hf[e] = bf2f(hv0[e]); hf[8+e] = bf2f(hv1[e]); }
      for (int rr = wv; rr < 25; rr += 4){
        const unsigned short* pr = PencL + rr*1024 + l*16;
        u16x8 p0 = *(const u16x8*)pr;
        u16x8 p1 = *(const u16x8*)(pr + 8);
        float sc = 0.f;
        #pragma unroll
        for (int e = 0; e < 8; ++e) sc += hf[e]*bf2f(p0[e]);
        #pragma unroll
        for (int e = 0; e < 8; ++e) sc += hf[8+e]*bf2f(p1[e]);
        #pragma unroll
        for (int o = 1; o < 64; o <<= 1) sc += __shfl_xor(sc, o);
        if (l == 0){
          float es = expf(sc);
          float aold = accL[rr];
          float denom = (i == 0) ? 1.f : aold;
          accL[rr] = aold + es;
          epL[rr] = es / denom;
        }
      }
      __syncthreads();
      float tot = 0.f;
      for (int rr = 0; rr < 25; ++rr) tot += epL[rr];
      float a0=0.f,a1=0.f,a2=0.f,a3=0.f;
      const unsigned short* ebase = enc_out + ((size_t)b_att*TE_ + tr*25)*H2_ + tid*4;
      for (int rr = 0; rr < 25; ++rr){
        float wgt = epL[rr];
        u16x4 ev = *(const u16x4*)(ebase + (size_t)rr*H2_);
        a0 += wgt*bf2f(ev[0]); a1 += wgt*bf2f(ev[1]); a2 += wgt*bf2f(ev[2]); a3 += wgt*bf2f(ev[3]);
      }
      float* dst = ctxn + p*16384 + (size_t)b_att*H2_ + tid*4;
      atomicAdd(dst+0, a0); atomicAdd(dst+1, a1); atomicAdd(dst+2, a2); atomicAdd(dst+3, a3);
      if (tid == 0) atomicAdd(psumT + p*16 + b_att, tot);
    }
    // dec-attention (64 owner WGs, quarter-column split)
    if (isDec){
      int col = qd*256 + tid;
      if (i == 0){
        xbuf[(size_t)b_dec*H2_ + col] = 0;
        Av[((size_t)b_dec*TD_ + i)*3072 + 2048 + col] = 0;
      } else {
        if (tid == 0) d_poll(bars, instV, 256);
        __syncthreads();
        const unsigned short* hq = hreg + p*16384 + (size_t)b_dec*H2_ + l*16;
        u16x8 h0v = *(const u16x8*)hq;
        u16x8 h1v = *(const u16x8*)(hq + 8);
        float qf[16];
        #pragma unroll
        for (int e = 0; e < 8; ++e){ qf[e] = bf2f(h0v[e]); qf[8+e] = bf2f(h1v[e]); }
        for (int tp = wv; tp < i; tp += 4){
          const unsigned short* vr = vbuf + ((size_t)tp*16 + b_dec)*H2_ + l*16;
          u16x8 e0 = *(const u16x8*)vr;
          u16x8 e1 = *(const u16x8*)(vr + 8);
          float sc = 0.f;
          #pragma unroll
          for (int e = 0; e < 8; ++e) sc += qf[e]*bf2f(e0[e]);
          #pragma unroll
          for (int e = 0; e < 8; ++e) sc += qf[8+e]*bf2f(e1[e]);
          #pragma unroll
          for (int o = 1; o < 64; o <<= 1) sc += __shfl_xor(sc, o);
          if (l == 0) dscL[tp] = sc;
        }
        __syncthreads();
        float m = -1e30f;
        for (int tp = 0; tp < i; ++tp) m = fmaxf(m, dscL[tp]);
        float ssum = 0.f;
        for (int tp = 0; tp < i; ++tp) ssum += expf(dscL[tp]-m);
        float inv = 1.f/ssum;
        float c_ = 0.f;
        for (int tp = 0; tp < i; ++tp){
          float wt = expf(dscL[tp]-m)*inv;
          c_ += wt*bf2f(bufh[((size_t)tp*16 + b_dec)*H2_ + col]);
        }
        unsigned short cb = f2bf(c_);
        xbuf[(size_t)b_dec*H2_ + col] = cb;
        Av[((size_t)b_dec*TD_ + i)*3072 + 2048 + col] = cb;
      }
    }
    if (tid == 0){ d_arrive(bars, instX); d_poll(bars, instX, 256); }
    __syncthreads();
    // ======== phase 2 ========
    asm volatile("s_waitcnt vmcnt(0)" ::: "memory");
    if (w < 64){   // Av ctx_e slice (cols w*16..+16)
      int b2 = tid >> 4, cs = tid & 15;
      float val = ctxn[p*16384 + (size_t)b2*H2_ + w*16 + cs] / psumT[p*16 + b2];
      Av[((size_t)b2*TD_ + i)*3072 + 1024 + w*16 + cs] = f2bf(val);
    }
    // ph2a: z += Wctx_e @ ctx_e (A from ctxn, normalized on the fly)
    {
      float invb = 1.f / psumT[p*16 + (l&15)];
      int kbase = wv*256;
      const float* cbase = ctxn + p*16384 + (size_t)(l&15)*H2_ + kbase + (l>>4)*8;
      #pragma unroll
      for (int ks = 0; ks < 8; ++ks){
        float4 v0 = *(const float4*)(cbase + ks*32);
        float4 v1 = *(const float4*)(cbase + ks*32 + 4);
        u16x8 afv;
        afv[0]=f2bf(v0.x*invb); afv[1]=f2bf(v0.y*invb); afv[2]=f2bf(v0.z*invb); afv[3]=f2bf(v0.w*invb);
        afv[4]=f2bf(v1.x*invb); afv[5]=f2bf(v1.y*invb); afv[6]=f2bf(v1.z*invb); afv[7]=f2bf(v1.w*invb);
        const char* sbL = myWB + (size_t)(ks>>2)*4096;
        int k8 = (ks&3)*4 + (l>>4);
        s16x8 bfr = *(const s16x8*)(sbL + (l&15)*256 + ((k8*16) ^ swz));
        if (ks & 1) accz1 = __builtin_amdgcn_mfma_f32_16x16x32_bf16((s16x8)afv, bfr, accz1, 0,0,0);
        else        accz0 = __builtin_amdgcn_mfma_f32_16x16x32_bf16((s16x8)afv, bfr, accz0, 0,0,0);
      }
    }
    // ph2b: z += Wctx_d @ ctx_d (A from xbuf bf16)
    {
      int kbase = wv*256;
      #pragma unroll
      for (int ks = 0; ks < 8; ++ks){
        s16x8 afr = *(const s16x8*)(xbuf + (size_t)(l&15)*H2_ + kbase + ks*32 + (l>>4)*8);
        const char* sbL = myWB + (size_t)(2 + (ks>>2))*4096;
        int k8 = (ks&3)*4 + (l>>4);
        s16x8 bfr = *(const s16x8*)(sbL + (l&15)*256 + ((k8*16) ^ swz));
        if (ks & 1) accz1 = __builtin_amdgcn_mfma_f32_16x16x32_bf16(afr, bfr, accz1, 0,0,0);
        else        accz0 = __builtin_amdgcn_mfma_f32_16x16x32_bf16(afr, bfr, accz0, 0,0,0);
      }
    }
    // cross-wave K reduce (2 rounds into 8KB)
    f32x4 accs = accz0 + accz1;
    if (wv < 2){
      #pragma unroll
      for (int j = 0; j < 4; ++j)
        zl[wv*1024 + ((l>>4)*4+j)*16 + (l&15)] = accs[j];
    }
    __syncthreads();
    if (wv >= 2){
      #pragma unroll
      for (int j = 0; j < 4; ++j)
        zl[(wv-2)*1024 + ((l>>4)*4+j)*16 + (l&15)] += accs[j];
    }
    __syncthreads();
    // gates (64 threads: 16 batch x 4 units)
    if (tid < 64){
      int b2 = tid >> 2, uloc = tid & 3;
      float zi = zl[b2*16 + 0*4 + uloc] + zl[1024 + b2*16 + 0*4 + uloc];
      float zf = zl[b2*16 + 1*4 + uloc] + zl[1024 + b2*16 + 1*4 + uloc];
      float zg = zl[b2*16 + 2*4 + uloc] + zl[1024 + b2*16 + 2*4 + uloc];
      float zo = zl[b2*16 + 3*4 + uloc] + zl[1024 + b2*16 + 3*4 + uloc];
      float iv = sigmoidf_(zi), fv = sigmoidf_(zf), gv = tanhf(zg), ov = sigmoidf_(zo);
      float cc = fv*creg + iv*gv;
      float hh = ov*tanhf(cc);
      creg = cc;
      int u = w*4 + uloc;
      unsigned short hb2 = f2bf(hh);
      hreg[((i+1)&1)*16384 + (size_t)b2*H2_ + u] = hb2;
      Av[((size_t)b2*TD_ + i)*3072 + u] = hb2;
      bufh[((size_t)i*16 + b2)*H2_ + u] = hb2;
      if (i == TD_-1){
        outHC[(size_t)b2*H2_ + u] = hh;
        outHC[16384 + (size_t)b2*H2_ + u] = cc;
      }
    }
    __syncthreads();
    if (tid == 0){ d_arrive(bars, instY); d_poll(bars, instY, 256); }
    __syncthreads();
  }
}

// ---------------- vocab GEMM ----------------
__global__ void __launch_bounds__(256, 2) k_vocab_gemm(
    const unsigned short* __restrict__ Av,
    const float* __restrict__ Wv,
    const float* __restrict__ bv,
    float* __restrict__ out)
{
  __shared__ unsigned short Ab[128*72];
  __shared__ unsigned short Bt[128*72];
  int p = blockIdx.x;
  int mt = (p>>3)&7, nt = (p&7) + 8*(p>>6);
  if (nt >= 250) return;
  int m0 = mt*128, n0 = nt*128;
  int tid = threadIdx.x, wvv = tid>>6, l = tid&63;
  int wr = wvv>>1, wc = wvv&1;
  f32x4 zero4 = {0.f,0.f,0.f,0.f};
  f32x4 acc[4][4];
  #pragma unroll
  for (int a=0;a<4;++a){
    #pragma unroll
    for (int b=0;b<4;++b) acc[a][b] = zero4;
  }
  for (int k0 = 0; k0 < 3072; k0 += 64){
    #pragma unroll
    for (int qq = 0; qq < 4; ++qq){
      int idx8 = (tid + qq*256)*8;
      int r = idx8 >> 6, k = idx8 & 63;
      *(u16x8*)(Ab + r*72 + k) = *(const u16x8*)(Av + (size_t)(m0+r)*3072 + k0 + k);
    }
    #pragma unroll
    for (int qq = 0; qq < 4; ++qq){
      int idx8 = (tid + qq*256)*8;
      int r = idx8 >> 6, k = idx8 & 63;
      const float* src = Wv + (size_t)(n0+r)*3072 + k0 + k;
      float4 v0 = *(const float4*)src;
      float4 v1 = *(const float4*)(src+4);
      u16x8 o;
      o[0]=f2bf(v0.x); o[1]=f2bf(v0.y); o[2]=f2bf(v0.z); o[3]=f2bf(v0.w);
      o[4]=f2bf(v1.x); o[5]=f2bf(v1.y); o[6]=f2bf(v1.z); o[7]=f2bf(v1.w);
      *(u16x8*)(Bt + r*72 + k) = o;
    }
    __syncthreads();
    #pragma unroll
    for (int ks = 0; ks < 2; ++ks){
      s16x8 af[4], bf[4];
      #pragma unroll
      for (int fi=0;fi<4;++fi)
        af[fi] = *(const s16x8*)(Ab + (wr*64+fi*16+(l&15))*72 + ks*32 + (l>>4)*8);
      #pragma unroll
      for (int fj=0;fj<4;++fj)
        bf[fj] = *(const s16x8*)(Bt + (wc*64+fj*16+(l&15))*72 + ks*32 + (l>>4)*8);
      #pragma unroll
      for (int fi=0;fi<4;++fi){
        #pragma unroll
        for (int fj=0;fj<4;++fj)
          acc[fi][fj] = __builtin_amdgcn_mfma_f32_16x16x32_bf16(af[fi], bf[fj], acc[fi][fj], 0,0,0);
      }
    }
    __syncthreads();
  }
  #pragma unroll
  for (int fj=0;fj<4;++fj){
    int col = n0 + wc*64 + fj*16 + (l&15);
    float bias = bv[col];
    #pragma unroll
    for (int fi=0;fi<4;++fi){
      #pragma unroll
      for (int j=0;j<4;++j){
        int row = m0 + wr*64 + fi*16 + (l>>4)*4 + j;
        out[(size_t)row*V_ + col] = acc[fi][fj][j] + bias;
      }
    }
  }
}

// ---------------- in-place log-softmax ----------------
__global__ void k_logsoftmax(float* __restrict__ out){
  int row = blockIdx.x;
  float* x = out + (size_t)row*V_;
  int tid = threadIdx.x;
  __shared__ float red[64];
  float m = -1e30f;
  for (int c = tid; c < V_; c += 256) m = fmaxf(m, x[c]);
  #pragma unroll
  for (int o=1;o<64;o<<=1) m = fmaxf(m, __shfl_xor(m,o));
  if ((tid&63)==0) red[tid>>6] = m;
  __syncthreads();
  m = fmaxf(fmaxf(red[0],red[1]), fmaxf(red[2],red[3]));
  float s = 0.f;
  for (int c = tid; c < V_; c += 256) s += expf(x[c]-m);
  #pragma unroll
  for (int o=1;o<64;o<<=1) s += __shfl_xor(s,o);
  if ((tid&63)==0) red[8 + (tid>>6)] = s;
  __syncthreads();
  s = red[8]+red[9]+red[10]+red[11];
  float lse = m + logf(s);
  for (int c = tid; c < V_; c += 256) x[c] = x[c] - lse;
}

extern "C" void kernel_launch(void* const* d_in, const int* in_sizes, int n_in,
                              void* d_out, int out_size, void* d_ws, size_t ws_size,
                              hipStream_t stream){
  (void)in_sizes; (void)n_in; (void)out_size; (void)ws_size;
  const int*   enc_in = (const int*)d_in[0];
  const int*   dec_in = (const int*)d_in[1];
  const float* h0   = (const float*)d_in[4];
  const float* c0   = (const float*)d_in[5];
  const float* emb  = (const float*)d_in[6];
  const float* Wih_f= (const float*)d_in[7];
  const float* Whh_f= (const float*)d_in[8];
  const float* b_f  = (const float*)d_in[9];
  const float* Wih_b= (const float*)d_in[10];
  const float* Whh_b= (const float*)d_in[11];
  const float* b_b  = (const float*)d_in[12];
  const float* Wih_d= (const float*)d_in[13];
  const float* Whh_d= (const float*)d_in[14];
  const float* b_d  = (const float*)d_in[15];
  const float* W_ea = (const float*)d_in[16];
  const float* W_da = (const float*)d_in[17];
  const float* W_v  = (const float*)d_in[18];
  const float* b_v  = (const float*)d_in[19];
  float* out = (float*)d_out;
  char* ws = (char*)d_ws;

  size_t o_bars   = 0;                                  // 99328 u32
  size_t o_ctxn   = 397312;
  size_t o_psumT  = o_ctxn + 131072;
  size_t o_xs     = o_psumT + 256;
  size_t o_decemb = o_xs + (size_t)6400*256*2;
  size_t o_Wenc   = o_decemb + (size_t)1024*256*2;
  size_t o_RWhh   = o_Wenc + (size_t)2*2048*768*2;
  size_t o_RWctx  = o_RWhh + (size_t)256*32768;
  size_t o_Wemb   = o_RWctx + (size_t)256*65536;
  size_t o_zinit  = o_Wemb + (size_t)4096*256*2;
  size_t o_zx     = o_zinit + (size_t)1024*4096*4;
  size_t o_enc    = o_zx + (size_t)2*6400*2048*2;
  size_t o_Penc   = o_enc + (size_t)16*400*1024*2;
  size_t o_hbuf   = o_Penc + (size_t)16*400*1024*2;
  size_t o_h0dec  = o_hbuf + (size_t)2*2*16*512*2;
  size_t o_c0dec  = o_h0dec + (size_t)16*1024*4;
  size_t o_hreg   = o_c0dec + (size_t)16*1024*4;
  size_t o_xbuf   = o_hreg + (size_t)2*16*1024*2;
  size_t o_vbuf   = o_xbuf + (size_t)16*1024*2;
  size_t o_bufh   = o_vbuf + (size_t)64*16*1024*2;
  size_t o_Av     = o_bufh + (size_t)64*16*1024*2;

  unsigned* bars        = (unsigned*)(ws + o_bars);
  float* ctxn           = (float*)(ws + o_ctxn);
  float* psumT          = (float*)(ws + o_psumT);
  unsigned short* xs    = (unsigned short*)(ws + o_xs);
  unsigned short* decemb= (unsigned short*)(ws + o_decemb);
  unsigned short* Wenc  = (unsigned short*)(ws + o_Wenc);
  char* RWhh            = ws + o_RWhh;
  char* RWctx           = ws + o_RWctx;
  unsigned short* Wemb  = (unsigned short*)(ws + o_Wemb);
  float* zinit          = (float*)(ws + o_zinit);
  unsigned short* zx    = (unsigned short*)(ws + o_zx);
  unsigned short* encO  = (unsigned short*)(ws + o_enc);
  unsigned short* Penc  = (unsigned short*)(ws + o_Penc);
  unsigned short* hbuf  = (unsigned short*)(ws + o_hbuf);
  float* h0dec          = (float*)(ws + o_h0dec);
  float* c0dec          = (float*)(ws + o_c0dec);
  unsigned short* hreg  = (unsigned short*)(ws + o_hreg);
  unsigned short* xbuf  = (unsigned short*)(ws + o_xbuf);
  unsigned short* vbuf  = (unsigned short*)(ws + o_vbuf);
  unsigned short* bufh  = (unsigned short*)(ws + o_bufh);
  unsigned short* Av    = (unsigned short*)(ws + o_Av);

  hipFuncSetAttribute((const void*)k_encoder, hipFuncAttributeMaxDynamicSharedMemorySize, 90000);
  hipFuncSetAttribute((const void*)k_decoder, hipFuncAttributeMaxDynamicSharedMemorySize, DEC_SMEM);

  k_init<<<392, 256, 0, stream>>>(bars, ctxn, psumT);
  k_gather<<<1600, 256, 0, stream>>>(emb, enc_in, xs, TE_);
  k_gather<<<256, 256, 0, stream>>>(emb, dec_in, decemb, TD_);
  k_prep_enc<<<1536, 256, 0, stream>>>(Wih_f, Whh_f, Wih_b, Whh_b, Wenc);
  k_prep_wihemb<<<512, 256, 0, stream>>>(Wih_d, Wemb);
  k_zinit<<<256, 256, 0, stream>>>(decemb, Wemb, b_d, zinit);
  k_zx<<<1600, 256, 0, stream>>>(xs, Wenc, b_f, b_b, zx);
  k_encoder<<<208, 256, 87296, stream>>>(zx, Wenc, h0, c0, encO, hbuf, h0dec, c0dec, bars,
                                         Whh_d, Wih_d, RWhh, RWctx);
  k_penc<<<400, 256, 0, stream>>>(encO, W_ea, Penc);
  k_dec_init<<<64, 256, 0, stream>>>(h0dec, hreg);
  k_decoder<<<256, 256, DEC_SMEM, stream>>>(RWhh, RWctx, zinit, Penc, encO, W_da, c0dec,
                                            hreg, xbuf, ctxn, psumT, vbuf, bufh, Av,
                                            out + (size_t)32768000, bars);
  k_vocab_gemm<<<2048, 256, 0, stream>>>(Av, W_v, b_v, out);
  k_logsoftmax<<<1024, 256, 0, stream>>>(out);
}

// Round 9
// 5337.054 us; speedup vs baseline: 1.3543x; 1.3543x over previous
//
#include <hip/hip_runtime.h>
#include <math.h>

#define B_  16
#define TE_ 400
#define TD_ 64
#define E_  256
#define H_  512
#define H2_ 1024
#define V_  32000

typedef __attribute__((ext_vector_type(4))) float f32x4;
typedef __attribute__((ext_vector_type(8))) short s16x8;
typedef __attribute__((ext_vector_type(8))) unsigned short u16x8;
typedef __attribute__((ext_vector_type(4))) unsigned short u16x4;

__device__ __forceinline__ float bf2f(unsigned short u){
  union { unsigned int i; float f; } v; v.i = ((unsigned int)u) << 16; return v.f;
}
__device__ __forceinline__ unsigned short f2bf(float f){
  union { float f; unsigned int i; } v; v.f = f;
  return (unsigned short)((v.i + 0x7fffu + ((v.i >> 16) & 1u)) >> 16);
}
__device__ __forceinline__ float sigmoidf_(float x){ return 1.f/(1.f + expf(-x)); }

__device__ __forceinline__ void gl_lds16(const void* gsrc, void* ldst){
  __builtin_amdgcn_global_load_lds(
      (const __attribute__((address_space(1))) unsigned int*)gsrc,
      (__attribute__((address_space(3))) unsigned int*)ldst, 16, 0, 0);
}

// paged one-shot barrier: 8 x 16KB pages (distinct L2 homes), inst*64B within page
__device__ __forceinline__ void d_arrive(unsigned* bars, int inst){
  __threadfence();
  __hip_atomic_fetch_add(bars + (blockIdx.x & 7u)*4096 + inst*16, 1u, __ATOMIC_RELAXED, __HIP_MEMORY_SCOPE_AGENT);
}
__device__ __forceinline__ void d_poll(unsigned* bars, int inst, unsigned tgt){
  int it = 0;
  for(;;){
    unsigned s = 0;
    #pragma unroll
    for (int k = 0; k < 8; ++k)
      s += __hip_atomic_load(bars + k*4096 + inst*16, __ATOMIC_RELAXED, __HIP_MEMORY_SCOPE_AGENT);
    if (s >= tgt) break;
    if (it < 6) __builtin_amdgcn_s_sleep(1);
    else if (it < 24) __builtin_amdgcn_s_sleep(4);
    else __builtin_amdgcn_s_sleep(16);
    ++it;
  }
  __threadfence();
}

// ---------------- init ----------------
__global__ void k_init(unsigned* bars, float* ctxn, float* psumT){
  int gid = blockIdx.x*256 + threadIdx.x;
  if (gid < 99328) bars[gid] = 0u;
  if (gid < 32768) ctxn[gid] = 0.f;
  if (gid < 32) psumT[gid] = 0.f;
}

// ---------------- embedding gather ----------------
__global__ void k_gather(const float* __restrict__ emb, const int* __restrict__ idx,
                         unsigned short* __restrict__ out, int T){
  int wv = threadIdx.x >> 6, l = threadIdx.x & 63;
  int row = blockIdx.x*4 + wv;
  if (row >= T*B_) return;
  int t = row >> 4, b = row & 15;
  int tok = idx[b*T + t];
  float4 v = *(const float4*)(emb + (size_t)tok*E_ + l*4);
  u16x4 o; o[0]=f2bf(v.x); o[1]=f2bf(v.y); o[2]=f2bf(v.z); o[3]=f2bf(v.w);
  *(u16x4*)(out + (size_t)row*E_ + l*4) = o;
}

// ---------------- prep encoder weights: gate-grouped [dir][2048][768] ----------------
__global__ void k_prep_enc(const float* __restrict__ Wih_f, const float* __restrict__ Whh_f,
                           const float* __restrict__ Wih_b, const float* __restrict__ Whh_b,
                           unsigned short* __restrict__ Wenc){
  int it = blockIdx.x*256 + threadIdx.x;
  int dir = it / (2048*96); int rem = it % (2048*96);
  int pr = rem / 96; int kc = rem % 96; int k0 = kc*8;
  int g = pr >> 6, r = pr & 63, gate = r >> 4, ul = r & 15;
  int orig = gate*H_ + g*16 + ul;
  const float* Wih = dir ? Wih_b : Wih_f;
  const float* Whh = dir ? Whh_b : Whh_f;
  u16x8 o;
  #pragma unroll
  for (int e = 0; e < 8; ++e){
    int k = k0 + e;
    float v = (k < E_) ? Wih[(size_t)orig*E_ + k] : Whh[(size_t)orig*H_ + (k - E_)];
    o[e] = f2bf(v);
  }
  *(u16x8*)(Wenc + ((size_t)dir*2048 + pr)*768 + k0) = o;
}

// WhExt: [64 g][8 kblk][20480B] = 16KB Whh gate-rows | 4KB W_da ROWS (for v=W_da@h)
__device__ __forceinline__ void prep_whext_item(int it, const float* __restrict__ Whh_d,
                                                const float* __restrict__ W_da,
                                                char* __restrict__ WhExt){
  if (it < 524288){
    int g = it >> 13; int rem = it & 8191;
    int kblk = rem >> 10; int rem2 = rem & 1023;
    int row = rem2 >> 4; int k8 = rem2 & 15;
    int gate = row >> 4, ul = row & 15;
    int orig = gate*H2_ + g*16 + ul;
    u16x8 o;
    #pragma unroll
    for (int e = 0; e < 8; ++e)
      o[e] = f2bf(Whh_d[(size_t)orig*H2_ + kblk*128 + k8*8 + e]);
    size_t off = (size_t)g*163840 + (size_t)kblk*20480 + (size_t)(row*256 + ((k8*16) ^ ((row&7)<<4)));
    *(u16x8*)(WhExt + off) = o;
  } else if (it < 655360){
    int qi = it - 524288;
    int g = qi >> 11; int rem = qi & 2047;
    int kblk = rem >> 8; int c2 = rem & 255;
    int wvv = c2 >> 6, rr = (c2 >> 2) & 15, c = c2 & 3;
    int row = g*16 + rr;                      // W_da ROW (v = W_da @ h)
    u16x8 o;
    #pragma unroll
    for (int e = 0; e < 8; ++e)
      o[e] = f2bf(W_da[(size_t)row*H2_ + kblk*128 + wvv*32 + c*8 + e]);
    size_t off = (size_t)g*163840 + (size_t)kblk*20480 + 16384
               + (size_t)(wvv*1024 + rr*64 + ((c*16) ^ ((rr&3)<<4)));
    *(u16x8*)(WhExt + off) = o;
  }
}

// CtxW: [64 g][16 kblk][16384B] from Wih_d cols 256..2303
__device__ __forceinline__ void prep_ctx_item(int it, const float* __restrict__ Wih_d,
                                              char* __restrict__ CtxW){
  int g = it >> 14; int rem = it & 16383;
  int kblk = rem >> 10; int rem2 = rem & 1023;
  int row = rem2 >> 4; int k8 = rem2 & 15;
  int gate = row >> 4, ul = row & 15;
  int orig = gate*H2_ + g*16 + ul;
  int k = 256 + kblk*128 + k8*8;
  u16x8 o;
  #pragma unroll
  for (int e = 0; e < 8; ++e)
    o[e] = f2bf(Wih_d[(size_t)orig*2304 + k + e]);
  size_t off = (size_t)g*262144 + (size_t)kblk*16384 + (size_t)(row*256 + ((k8*16) ^ ((row&7)<<4)));
  *(u16x8*)(CtxW + off) = o;
}

// ---------------- prep WihEmbGrp [4096][256] ----------------
__global__ void k_prep_wihemb(const float* __restrict__ Wih_d, unsigned short* __restrict__ Wemb){
  int it = blockIdx.x*256 + threadIdx.x;
  int p = it >> 5; int k0 = (it & 31)*8;
  int g = p >> 6, gate = (p >> 4) & 3, ul = p & 15;
  int orig = gate*H2_ + g*16 + ul;
  u16x8 o;
  #pragma unroll
  for (int e = 0; e < 8; ++e)
    o[e] = f2bf(Wih_d[(size_t)orig*2304 + k0 + e]);
  *(u16x8*)(Wemb + (size_t)p*256 + k0) = o;
}

// ---------------- zinit GEMM: [1024][4096] f32 = decemb @ WihEmbGrp^T + b_d ----------------
__global__ void __launch_bounds__(256, 2) k_zinit(
    const unsigned short* __restrict__ A,
    const unsigned short* __restrict__ Bw,
    const float* __restrict__ bd,
    float* __restrict__ Cz)
{
  __shared__ unsigned short Ab[128*72];
  __shared__ unsigned short Bt[128*72];
  int p = blockIdx.x;
  int mt = p >> 5, nt = p & 31;
  int m0 = mt*128, n0 = nt*128;
  int tid = threadIdx.x, wvv = tid>>6, l = tid&63;
  int wr = wvv>>1, wc = wvv&1;
  f32x4 zero4 = {0.f,0.f,0.f,0.f};
  f32x4 acc[4][4];
  #pragma unroll
  for (int a=0;a<4;++a){
    #pragma unroll
    for (int b=0;b<4;++b) acc[a][b] = zero4;
  }
  for (int k0 = 0; k0 < 256; k0 += 64){
    #pragma unroll
    for (int qq = 0; qq < 4; ++qq){
      int idx8 = (tid + qq*256)*8;
      int r = idx8 >> 6, k = idx8 & 63;
      *(u16x8*)(Ab + r*72 + k) = *(const u16x8*)(A + (size_t)(m0+r)*256 + k0 + k);
      *(u16x8*)(Bt + r*72 + k) = *(const u16x8*)(Bw + (size_t)(n0+r)*256 + k0 + k);
    }
    __syncthreads();
    #pragma unroll
    for (int ks = 0; ks < 2; ++ks){
      s16x8 af[4], bf[4];
      #pragma unroll
      for (int fi=0;fi<4;++fi)
        af[fi] = *(const s16x8*)(Ab + (wr*64+fi*16+(l&15))*72 + ks*32 + (l>>4)*8);
      #pragma unroll
      for (int fj=0;fj<4;++fj)
        bf[fj] = *(const s16x8*)(Bt + (wc*64+fj*16+(l&15))*72 + ks*32 + (l>>4)*8);
      #pragma unroll
      for (int fi=0;fi<4;++fi){
        #pragma unroll
        for (int fj=0;fj<4;++fj)
          acc[fi][fj] = __builtin_amdgcn_mfma_f32_16x16x32_bf16(af[fi], bf[fj], acc[fi][fj], 0,0,0);
      }
    }
    __syncthreads();
  }
  #pragma unroll
  for (int fj=0;fj<4;++fj){
    int col = n0 + wc*64 + fj*16 + (l&15);
    int orig = ((col>>4)&3)*H2_ + (col>>6)*16 + (col&15);
    float bias = bd[orig];
    #pragma unroll
    for (int fi=0;fi<4;++fi){
      #pragma unroll
      for (int j=0;j<4;++j){
        int row = m0 + wr*64 + fi*16 + (l>>4)*4 + j;
        Cz[(size_t)row*4096 + col] = acc[fi][fj][j] + bias;
      }
    }
  }
}

// ---------------- zx GEMM: zx[dir][6400][2048] bf16 = xs @ WihGrp^T + b ----------------
__global__ void __launch_bounds__(256, 2) k_zx(
    const unsigned short* __restrict__ xs,
    const unsigned short* __restrict__ Wenc,
    const float* __restrict__ b_f, const float* __restrict__ b_b,
    unsigned short* __restrict__ zx)
{
  __shared__ unsigned short Ab[128*72];
  __shared__ unsigned short Bt[128*72];
  int pblk = blockIdx.x;
  int dir = pblk / 800; int rem = pblk % 800;
  int mt = rem >> 4, nt = rem & 15;
  int m0 = mt*128, n0 = nt*128;
  int tid = threadIdx.x, wvv = tid>>6, l = tid&63;
  int wr = wvv>>1, wc = wvv&1;
  f32x4 zero4 = {0.f,0.f,0.f,0.f};
  f32x4 acc[4][4];
  #pragma unroll
  for (int a=0;a<4;++a){
    #pragma unroll
    for (int b=0;b<4;++b) acc[a][b] = zero4;
  }
  for (int k0 = 0; k0 < 256; k0 += 64){
    #pragma unroll
    for (int qq = 0; qq < 4; ++qq){
      int idx8 = (tid + qq*256)*8;
      int r = idx8 >> 6, k = idx8 & 63;
      *(u16x8*)(Ab + r*72 + k) = *(const u16x8*)(xs + (size_t)(m0+r)*256 + k0 + k);
      *(u16x8*)(Bt + r*72 + k) = *(const u16x8*)(Wenc + ((size_t)dir*2048 + n0+r)*768 + k0 + k);
    }
    __syncthreads();
    #pragma unroll
    for (int ks = 0; ks < 2; ++ks){
      s16x8 af[4], bf[4];
      #pragma unroll
      for (int fi=0;fi<4;++fi)
        af[fi] = *(const s16x8*)(Ab + (wr*64+fi*16+(l&15))*72 + ks*32 + (l>>4)*8);
      #pragma unroll
      for (int fj=0;fj<4;++fj)
        bf[fj] = *(const s16x8*)(Bt + (wc*64+fj*16+(l&15))*72 + ks*32 + (l>>4)*8);
      #pragma unroll
      for (int fi=0;fi<4;++fi){
        #pragma unroll
        for (int fj=0;fj<4;++fj)
          acc[fi][fj] = __builtin_amdgcn_mfma_f32_16x16x32_bf16(af[fi], bf[fj], acc[fi][fj], 0,0,0);
      }
    }
    __syncthreads();
  }
  const float* bsrc = dir ? b_b : b_f;
  #pragma unroll
  for (int fj=0;fj<4;++fj){
    int col = n0 + wc*64 + fj*16 + (l&15);
    float bias = bsrc[((col>>4)&3)*512 + (col>>6)*16 + (col&15)];
    #pragma unroll
    for (int fi=0;fi<4;++fi){
      #pragma unroll
      for (int j=0;j<4;++j){
        int row = m0 + wr*64 + fi*16 + (l>>4)*4 + j;
        zx[((size_t)dir*6400 + row)*2048 + col] = f2bf(acc[fi][fj][j] + bias);
      }
    }
  }
}

// ---------------- Penc = enc_out @ W_ea^T (bf16) ----------------
__global__ void __launch_bounds__(256, 2) k_penc(
    const unsigned short* __restrict__ enc,
    const float* __restrict__ Wea,
    unsigned short* __restrict__ P)
{
  __shared__ unsigned short Ab[128*72];
  __shared__ unsigned short Bt[128*72];
  int p = blockIdx.x;
  int mt = p >> 3, nt = p & 7;
  int m0 = mt*128, n0 = nt*128;
  int tid = threadIdx.x, wvv = tid>>6, l = tid&63;
  int wr = wvv>>1, wc = wvv&1;
  f32x4 zero4 = {0.f,0.f,0.f,0.f};
  f32x4 acc[4][4];
  #pragma unroll
  for (int a=0;a<4;++a){
    #pragma unroll
    for (int b=0;b<4;++b) acc[a][b] = zero4;
  }
  for (int k0 = 0; k0 < 1024; k0 += 64){
    #pragma unroll
    for (int qq = 0; qq < 4; ++qq){
      int idx8 = (tid + qq*256)*8;
      int r = idx8 >> 6, k = idx8 & 63;
      *(u16x8*)(Ab + r*72 + k) = *(const u16x8*)(enc + (size_t)(m0+r)*1024 + k0 + k);
    }
    #pragma unroll
    for (int qq = 0; qq < 4; ++qq){
      int idx8 = (tid + qq*256)*8;
      int r = idx8 >> 6, k = idx8 & 63;
      const float* src = Wea + (size_t)(n0+r)*1024 + k0 + k;
      float4 v0 = *(const float4*)src;
      float4 v1 = *(const float4*)(src+4);
      u16x8 o;
      o[0]=f2bf(v0.x); o[1]=f2bf(v0.y); o[2]=f2bf(v0.z); o[3]=f2bf(v0.w);
      o[4]=f2bf(v1.x); o[5]=f2bf(v1.y); o[6]=f2bf(v1.z); o[7]=f2bf(v1.w);
      *(u16x8*)(Bt + r*72 + k) = o;
    }
    __syncthreads();
    #pragma unroll
    for (int ks = 0; ks < 2; ++ks){
      s16x8 af[4], bf[4];
      #pragma unroll
      for (int fi=0;fi<4;++fi)
        af[fi] = *(const s16x8*)(Ab + (wr*64+fi*16+(l&15))*72 + ks*32 + (l>>4)*8);
      #pragma unroll
      for (int fj=0;fj<4;++fj)
        bf[fj] = *(const s16x8*)(Bt + (wc*64+fj*16+(l&15))*72 + ks*32 + (l>>4)*8);
      #pragma unroll
      for (int fi=0;fi<4;++fi){
        #pragma unroll
        for (int fj=0;fj<4;++fj)
          acc[fi][fj] = __builtin_amdgcn_mfma_f32_16x16x32_bf16(af[fi], bf[fj], acc[fi][fj], 0,0,0);
      }
    }
    __syncthreads();
  }
  #pragma unroll
  for (int fj=0;fj<4;++fj){
    int col = n0 + wc*64 + fj*16 + (l&15);
    #pragma unroll
    for (int fi=0;fi<4;++fi){
      #pragma unroll
      for (int j=0;j<4;++j){
        int row = m0 + wr*64 + fi*16 + (l>>4)*4 + j;
        P[(size_t)row*1024 + col] = f2bf(acc[fi][fj][j]);
      }
    }
  }
}

// ---------------- persistent bi-LSTM encoder (K=512, zx-init) + prep WGs ----------------
__global__ void __launch_bounds__(256, 1) k_encoder(
    const unsigned short* __restrict__ zx,
    const unsigned short* __restrict__ Wenc,
    const float* __restrict__ h0, const float* __restrict__ c0,
    unsigned short* __restrict__ enc_out,
    unsigned short* __restrict__ hbuf,
    float* __restrict__ h0dec, float* __restrict__ c0dec,
    unsigned* __restrict__ bars,
    const float* __restrict__ Whh_d, const float* __restrict__ W_da,
    const float* __restrict__ Wih_d,
    char* __restrict__ WhExt, char* __restrict__ CtxW)
{
  extern __shared__ char smem[];
  int tid = threadIdx.x;
  int w = blockIdx.x;
  if (w >= 64){
    int base = (w - 64)*256 + tid;
    for (int it = base; it < 655360; it += 36864) prep_whext_item(it, Whh_d, W_da, WhExt);
    for (int it = base; it < 1048576; it += 36864) prep_ctx_item(it, Wih_d, CtxW);
    return;
  }
  unsigned short* Wt = (unsigned short*)smem;            // [64][520]
  unsigned short* At = Wt + 64*520;                      // [16][520]
  float* zl = (float*)(At + 16*520);                     // [4][16][16]
  int dir = w >> 5, g = w & 31;
  int wv = tid >> 6, l = tid & 63;
  unsigned* ebars = bars + 32768;
  {
    const unsigned short* Wsrc = Wenc + ((size_t)dir*2048 + g*64)*768 + 256;
    int r = tid >> 2, s = tid & 3;
    for (int c = 0; c < 16; ++c)
      *(u16x8*)(Wt + r*520 + s*128 + c*8) = *(const u16x8*)(Wsrc + (size_t)r*768 + s*128 + c*8);
  }
  int bb = tid >> 4, ul = tid & 15;
  float creg = c0[((size_t)dir*16 + bb)*H_ + g*16 + ul];
  int kchunk = (l >> 4) * 8;
  f32x4 zero4 = { 0.f, 0.f, 0.f, 0.f };
  {
    int r = tid >> 4, s = tid & 15;
    for (int e = 0; e < 32; ++e)
      At[r*520 + s*32 + e] = f2bf(h0[((size_t)dir*16 + r)*H_ + s*32 + e]);
  }
  int tg0 = dir ? (TE_-1) : 0;
  const unsigned short* zrow = zx + ((size_t)dir*6400 + (size_t)tg0*16 + (l>>4)*4)*2048 + g*64 + wv*16 + (l&15);
  f32x4 a0cur;
  a0cur[0]=bf2f(zrow[0]); a0cur[1]=bf2f(zrow[2048]); a0cur[2]=bf2f(zrow[4096]); a0cur[3]=bf2f(zrow[6144]);
  __syncthreads();
  for (int t = 0; t < TE_; ++t){
    int tg = dir ? (TE_-1 - t) : t;
    f32x4 acc0 = a0cur, acc1 = zero4;
    const unsigned short* brow = Wt + (wv*16 + (l&15))*520 + kchunk;
    const unsigned short* ap   = At + (l&15)*520 + kchunk;
    #pragma unroll
    for (int ks = 0; ks < 16; ++ks){
      s16x8 afr = *(const s16x8*)(ap + ks*32);
      s16x8 bfr = *(const s16x8*)(brow + ks*32);
      if (ks & 1) acc1 = __builtin_amdgcn_mfma_f32_16x16x32_bf16(afr, bfr, acc1, 0, 0, 0);
      else        acc0 = __builtin_amdgcn_mfma_f32_16x16x32_bf16(afr, bfr, acc0, 0, 0, 0);
    }
    f32x4 acc = acc0 + acc1;
    #pragma unroll
    for (int j = 0; j < 4; ++j)
      zl[wv*256 + ((l>>4)*4 + j)*16 + (l&15)] = acc[j];
    __syncthreads();
    float zi = zl[0*256 + bb*16 + ul];
    float zf = zl[1*256 + bb*16 + ul];
    float zg = zl[2*256 + bb*16 + ul];
    float zo = zl[3*256 + bb*16 + ul];
    float iv = sigmoidf_(zi), fv = sigmoidf_(zf), gv = tanhf(zg), ov = sigmoidf_(zo);
    float cc = fv*creg + iv*gv;
    float hh = ov * tanhf(cc);
    creg = cc;
    int u = g*16 + ul;
    unsigned short hb = f2bf(hh);
    hbuf[((size_t)dir*2 + ((t+1)&1))*(16*H_) + bb*H_ + u] = hb;
    enc_out[((size_t)bb*TE_ + tg)*H2_ + dir*H_ + u] = hb;
    if (t == TE_-1){
      h0dec[(size_t)bb*H2_ + dir*H_ + u] = hh;
      c0dec[(size_t)bb*H2_ + dir*H_ + u] = cc;
    }
    int inst = dir*400 + t;
    __syncthreads();
    if (tid == 0){
      __threadfence();
      __hip_atomic_fetch_add(ebars + (g&3)*16384 + inst*16, 1u, __ATOMIC_RELAXED, __HIP_MEMORY_SCOPE_AGENT);
    }
    if (t+1 < TE_){   // prefetch next zx during barrier wait (h-independent)
      int tg2 = dir ? (TE_-2 - t) : (t+1);
      const unsigned short* zr2 = zx + ((size_t)dir*6400 + (size_t)tg2*16 + (l>>4)*4)*2048 + g*64 + wv*16 + (l&15);
      a0cur[0]=bf2f(zr2[0]); a0cur[1]=bf2f(zr2[2048]); a0cur[2]=bf2f(zr2[4096]); a0cur[3]=bf2f(zr2[6144]);
    }
    if (tid == 0){
      int it = 0;
      for(;;){
        unsigned s_ = 0;
        #pragma unroll
        for (int k2 = 0; k2 < 4; ++k2)
          s_ += __hip_atomic_load(ebars + k2*16384 + inst*16, __ATOMIC_RELAXED, __HIP_MEMORY_SCOPE_AGENT);
        if (s_ >= 32) break;
        if (it < 6) __builtin_amdgcn_s_sleep(1);
        else __builtin_amdgcn_s_sleep(4);
        ++it;
      }
      __threadfence();
    }
    __syncthreads();
    if (t+1 < TE_){
      int r = tid >> 4, s = tid & 15;
      const unsigned short* hsrc = hbuf + ((size_t)dir*2 + ((t+1)&1))*(16*H_) + r*H_ + s*32;
      for (int c = 0; c < 4; ++c)
        *(u16x8*)(At + r*520 + s*32 + c*8) = *(const u16x8*)(hsrc + c*8);
    }
    __syncthreads();
  }
}

__global__ void k_dec_init(const float* __restrict__ h0dec, unsigned short* __restrict__ hreg){
  int gid = blockIdx.x*256 + threadIdx.x;
  if (gid < 16384) hreg[gid] = f2bf(h0dec[gid]);
}

// stream issue helpers
__device__ __forceinline__ void issueA(const char* gA, char* BbA, int wv, int l, int kblk, int buf){
  const char* gsrc = gA + (size_t)kblk*20480;
  char* lb = BbA + buf*20480;
  #pragma unroll
  for (int q = 0; q < 4; ++q)
    gl_lds16(gsrc + wv*4096 + q*1024 + (size_t)l*16, lb + wv*4096 + q*1024);
  gl_lds16(gsrc + 16384 + wv*1024 + (size_t)l*16, lb + 16384 + wv*1024);
}
// C slots: 0,1 in BbC (16KB each); 2,3 in BbA region (offsets 0, 20480)
__device__ __forceinline__ char* cslot(char* BbA, char* BbC, int s){
  if (s < 2) return BbC + s*16384;
  return BbA + (s-2)*20480;
}
__device__ __forceinline__ void issueC(const char* gC, char* lb, int wv, int l, int kblk){
  const char* gsrc = gC + (size_t)kblk*16384;
  #pragma unroll
  for (int q = 0; q < 4; ++q)
    gl_lds16(gsrc + wv*4096 + q*1024 + (size_t)l*16, lb + wv*4096 + q*1024);
}

// ---------------- persistent attention decoder (208 WGs, 2 grid syncs + mini-M) ----------------
__global__ void __launch_bounds__(256, 1) k_decoder(
  const char* __restrict__ WhExt,       // [64][8*20480]
  const char* __restrict__ CtxW,        // [64][16*16384]
  const float* __restrict__ zinit,      // [1024][4096]
  const unsigned short* __restrict__ Penc,     // [6400][1024] bf16
  const unsigned short* __restrict__ enc_out,
  const float* __restrict__ c0dec,
  unsigned short* __restrict__ hreg,    // [2][16][1024] bf16
  unsigned short* __restrict__ xbuf,    // [16][1024] bf16 ctx_d
  float* __restrict__ ctxn,             // [2][16][1024]
  float* __restrict__ psumT,            // [2][16]
  unsigned short* __restrict__ vbuf,    // [64][16][1024] bf16 (W_da@bufh)
  unsigned short* __restrict__ bufh,    // [64][16][1024] bf16
  unsigned short* __restrict__ Av,      // [1024][3072]
  float* __restrict__ outHC,
  unsigned* __restrict__ bars)
{
  extern __shared__ char smem[];
  int tid = threadIdx.x, w = blockIdx.x;
  int wv = tid >> 6, l = tid & 63;

  unsigned short* Atc = (unsigned short*)smem;           // [16][2056]
  unsigned short* Ah  = (unsigned short*)smem;           // [16][1032]
  char* BbA = smem + 66560;                              // 3 x 20480
  char* BbC = smem + 128000;                             // 2 x 16384
  float* zq = (float*)(smem + 66560);                    // post-stream overlap
  float* zl = (float*)(smem + 128000);                   // post-stream overlap
  unsigned short* encL = (unsigned short*)smem;          // [50][1032]
  float* epL  = (float*)(smem + 103424);
  float* accL = (float*)(smem + 103680);
  float* dscL = (float*)smem;                            // dec-attn WGs

  bool isZ = (w < 64);
  bool isE = (w >= 64 && w < 192);
  int eb = 0, ec = 0;
  if (isE){ eb = (w-64) >> 3; ec = (w-64) & 7; }
  int db = w - 192;

  if (isE){
    for (int rr = 0; rr < 50; ++rr){
      const unsigned short* src = enc_out + ((size_t)eb*TE_ + ec*50 + rr)*H2_;
      *(u16x4*)(encL + rr*1032 + tid*4) = *(const u16x4*)(src + tid*4);
    }
    if (tid < 50) accL[tid] = 0.f;
    __syncthreads();
  }
  float creg = 0.f;
  int bb = tid >> 4, ul = tid & 15;
  const char* gA = WhExt + (size_t)w*163840;
  const char* gC = CtxW + (size_t)w*262144;
  // warming target for enc-attn WGs (same XCD: (w)%8 == target%8 since 64,128 ≡ 0 mod 8)
  const char* warmbase = 0; int warmhalf4 = 0;
  if (isE){
    int j = w - 64;
    if (j < 64){ warmbase = WhExt + (size_t)j*163840; warmhalf4 = 5120; }   // 80KB halves
    else       { warmbase = CtxW + (size_t)(j-64)*262144; warmhalf4 = 8192; } // 128KB halves
  }
  f32x4 acc0, acc1;

  if (isZ){  // initial pre-issue of SA blocks 0,1
    issueA(gA, BbA, wv, l, 0, 0);
    issueA(gA, BbA, wv, l, 1, 1);
  }

  for (int i = 0; i < TD_; ++i){
    int p = i & 1;
    int iM = i*3, iAb = i*3+1, iBb = i*3+2;

    if (isZ){
      // ---- phase 1: z += Whh@h ; v = W_da@h ----
      ctxn[(p^1)*16384 + w*256 + tid] = 0.f;
      if (w == 0 && tid < 16) psumT[(p^1)*16 + tid] = 0.f;
      const float* zsrc = zinit + ((size_t)i*16 + (l>>4)*4)*4096 + w*64 + wv*16 + (l&15);
      f32x4 a0i; a0i[0]=zsrc[0]; a0i[1]=zsrc[4096]; a0i[2]=zsrc[8192]; a0i[3]=zsrc[12288];
      {
        int r = tid >> 4, s = tid & 15;
        const unsigned short* hsrc = hreg + p*16384 + r*H2_ + s*64;
        for (int c = 0; c < 8; ++c)
          *(u16x8*)(Ah + r*1032 + s*64 + c*8) = *(const u16x8*)(hsrc + c*8);
      }
      __syncthreads();
      acc0 = a0i;
      f32x4 z4 = {0.f,0.f,0.f,0.f};
      acc1 = z4;
      f32x4 accv = z4;
      int swz = ((l&7)<<4);
      for (int kblk = 0; kblk < 8; ++kblk){
        int buf = kblk % 3;
        if (kblk + 2 < 8) issueA(gA, BbA, wv, l, kblk+2, (kblk+2)%3);
        if (kblk < 6)       asm volatile("s_waitcnt vmcnt(10)" ::: "memory");
        else if (kblk == 6) asm volatile("s_waitcnt vmcnt(5)" ::: "memory");
        else                asm volatile("s_waitcnt vmcnt(0)" ::: "memory");
        const unsigned short* ap = Ah + (l&15)*1032 + kblk*128 + (l>>4)*8;
        const char* Bz = BbA + buf*20480 + wv*4096;
        #pragma unroll
        for (int ks = 0; ks < 4; ++ks){
          int k8 = ks*4 + (l>>4);
          s16x8 afr = *(const s16x8*)(ap + ks*32);
          s16x8 bfr = *(const s16x8*)(Bz + (l&15)*256 + ((k8*16) ^ swz));
          if (ks & 1) acc1 = __builtin_amdgcn_mfma_f32_16x16x32_bf16(afr, bfr, acc1, 0,0,0);
          else        acc0 = __builtin_amdgcn_mfma_f32_16x16x32_bf16(afr, bfr, acc0, 0,0,0);
        }
        s16x8 afq = *(const s16x8*)(Ah + (l&15)*1032 + kblk*128 + wv*32 + (l>>4)*8);
        s16x8 bfv = *(const s16x8*)(BbA + buf*20480 + 16384 + wv*1024 + (l&15)*64 + ((((l>>4)*16)) ^ ((l&3)<<4)));
        accv = __builtin_amdgcn_mfma_f32_16x16x32_bf16(afq, bfv, accv, 0,0,0);
      }
      __syncthreads();    // streams done: safe to reuse BbA[0] as zq
      #pragma unroll
      for (int j = 0; j < 4; ++j)
        zq[wv*256 + ((l>>4)*4+j)*16 + (l&15)] = accv[j];
      __syncthreads();
      if (i > 0){
        float vv = zq[0*256+bb*16+ul] + zq[1*256+bb*16+ul] + zq[2*256+bb*16+ul] + zq[3*256+bb*16+ul];
        vbuf[((size_t)(i-1)*16 + bb)*H2_ + w*16 + ul] = f2bf(vv);
      }
      __syncthreads();
      if (tid == 0) d_arrive(bars, iM);
      // pre-issue phase-2 C blocks 0..3 (4 slots) under barA wait
      issueC(gC, cslot(BbA, BbC, 0), wv, l, 0);
      issueC(gC, cslot(BbA, BbC, 1), wv, l, 1);
      issueC(gC, cslot(BbA, BbC, 2), wv, l, 2);
      issueC(gC, cslot(BbA, BbC, 3), wv, l, 3);
      if (tid == 0) d_poll(bars, iAb, 144);
      __syncthreads();
      // ---- phase 2: z += Wctx@[ctx_e|ctx_d], gates ----
      {
        int r = tid >> 4, s = tid & 15;
        float inv = 1.f / psumT[p*16 + r];
        const float* cn = ctxn + p*16384 + (size_t)r*1024 + s*64;
        for (int c8 = 0; c8 < 8; ++c8){
          float4 v0 = *(const float4*)(cn + c8*8);
          float4 v1 = *(const float4*)(cn + c8*8 + 4);
          u16x8 o;
          o[0]=f2bf(v0.x*inv); o[1]=f2bf(v0.y*inv); o[2]=f2bf(v0.z*inv); o[3]=f2bf(v0.w*inv);
          o[4]=f2bf(v1.x*inv); o[5]=f2bf(v1.y*inv); o[6]=f2bf(v1.z*inv); o[7]=f2bf(v1.w*inv);
          *(u16x8*)(Atc + r*2056 + s*64 + c8*8) = o;
        }
        const unsigned short* xd = xbuf + (size_t)r*1024 + s*64;
        for (int c8 = 0; c8 < 8; ++c8)
          *(u16x8*)(Atc + r*2056 + 1024 + s*64 + c8*8) = *(const u16x8*)(xd + c8*8);
      }
      {
        float val = ctxn[p*16384 + (size_t)bb*1024 + w*16 + ul] / psumT[p*16 + bb];
        Av[((size_t)bb*TD_ + i)*3072 + 1024 + w*16 + ul] = f2bf(val);
      }
      __syncthreads();
      int swz2 = ((l&7)<<4);
      for (int k = 0; k < 16; ++k){
        int rem = 15 - k;
        if (rem >= 3)      asm volatile("s_waitcnt vmcnt(12)" ::: "memory");
        else if (rem == 2) asm volatile("s_waitcnt vmcnt(8)" ::: "memory");
        else if (rem == 1) asm volatile("s_waitcnt vmcnt(4)" ::: "memory");
        else               asm volatile("s_waitcnt vmcnt(0)" ::: "memory");
        const unsigned short* ap = Atc + (l&15)*2056 + k*128 + (l>>4)*8;
        const char* Bz = cslot(BbA, BbC, k&3) + wv*4096;
        #pragma unroll
        for (int ks = 0; ks < 4; ++ks){
          int k8 = ks*4 + (l>>4);
          s16x8 afr = *(const s16x8*)(ap + ks*32);
          s16x8 bfr = *(const s16x8*)(Bz + (l&15)*256 + ((k8*16) ^ swz2));
          if (ks & 1) acc1 = __builtin_amdgcn_mfma_f32_16x16x32_bf16(afr, bfr, acc1, 0,0,0);
          else        acc0 = __builtin_amdgcn_mfma_f32_16x16x32_bf16(afr, bfr, acc0, 0,0,0);
        }
        if (k + 4 < 16) issueC(gC, cslot(BbA, BbC, (k+4)&3), wv, l, k+4);
      }
      __syncthreads();    // streams done: reuse BbC[0] as zl
      f32x4 acc = acc0 + acc1;
      #pragma unroll
      for (int j = 0; j < 4; ++j)
        zl[wv*256 + ((l>>4)*4+j)*16 + (l&15)] = acc[j];
      __syncthreads();
      float zi = zl[0*256 + bb*16 + ul];
      float zf = zl[1*256 + bb*16 + ul];
      float zg = zl[2*256 + bb*16 + ul];
      float zo = zl[3*256 + bb*16 + ul];
      if (i == 0) creg = c0dec[(size_t)bb*H2_ + w*16 + ul];
      float iv = sigmoidf_(zi), fv = sigmoidf_(zf), gv = tanhf(zg), ov = sigmoidf_(zo);
      float cc = fv*creg + iv*gv;
      float hh = ov*tanhf(cc);
      creg = cc;
      int u = w*16 + ul;
      unsigned short hb2 = f2bf(hh);
      hreg[((i+1)&1)*16384 + (size_t)bb*H2_ + u] = hb2;
      Av[((size_t)bb*TD_ + i)*3072 + u] = hb2;
      bufh[((size_t)i*16 + bb)*H2_ + u] = hb2;
      if (i == TD_-1){
        outHC[(size_t)bb*H2_ + u] = hh;
        outHC[16384 + (size_t)bb*H2_ + u] = cc;
      }
      __syncthreads();
      if (tid == 0) d_arrive(bars, iBb);
      if (i + 1 < TD_){   // pre-issue next step's SA blocks under barB wait
        issueA(gA, BbA, wv, l, 0, 0);
        issueA(gA, BbA, wv, l, 1, 1);
      }
      if (tid == 0) d_poll(bars, iBb, 64);
      __syncthreads();
    } else if (isE){
      // ---- enc-attention (phase 1) ----
      const unsigned short* hb_ = hreg + p*16384 + eb*H2_ + l*16;
      u16x8 hv0 = *(const u16x8*)hb_;
      u16x8 hv1 = *(const u16x8*)(hb_ + 8);
      float hf[16];
      #pragma unroll
      for (int c = 0; c < 8; ++c){ hf[c] = bf2f(hv0[c]); hf[8+c] = bf2f(hv1[c]); }
      for (int rr = wv; rr < 50; rr += 4){
        const unsigned short* pr = Penc + ((size_t)(eb*TE_ + ec*50 + rr))*H2_ + l*16;
        u16x8 p0 = *(const u16x8*)pr;
        u16x8 p1 = *(const u16x8*)(pr + 8);
        float sc = 0.f;
        #pragma unroll
        for (int c = 0; c < 8; ++c) sc += hf[c]*bf2f(p0[c]);
        #pragma unroll
        for (int c = 0; c < 8; ++c) sc += hf[8+c]*bf2f(p1[c]);
        #pragma unroll
        for (int o = 1; o < 64; o <<= 1) sc += __shfl_xor(sc, o);
        if (l == 0){
          float es = expf(sc);
          float aold = accL[rr];
          float denom = (i == 0) ? 1.f : aold;
          accL[rr] = aold + es;
          epL[rr] = es / denom;
        }
      }
      __syncthreads();
      float tot = 0.f;
      for (int rr = 0; rr < 50; ++rr) tot += epL[rr];
      float a0=0.f,a1=0.f,a2=0.f,a3=0.f;
      for (int rr = 0; rr < 50; ++rr){
        float wgt = epL[rr];
        u16x4 ev = *(const u16x4*)(encL + rr*1032 + tid*4);
        a0 += wgt*bf2f(ev[0]); a1 += wgt*bf2f(ev[1]); a2 += wgt*bf2f(ev[2]); a3 += wgt*bf2f(ev[3]);
      }
      float* dst = ctxn + p*16384 + (size_t)eb*1024 + tid*4;
      atomicAdd(dst+0, a0); atomicAdd(dst+1, a1); atomicAdd(dst+2, a2); atomicAdd(dst+3, a3);
      if (tid == 0) atomicAdd(psumT + p*16 + eb, tot);
      __syncthreads();
      if (tid == 0) d_arrive(bars, iAb);
      // ---- warm same-XCD z-WG weight stream during barB slack (half per step) ----
      {
        const unsigned* wb = (const unsigned*)(warmbase + (size_t)(i & 1)*warmhalf4*16);
        unsigned accw = 0;
        for (int o = tid; o < warmhalf4; o += 256){
          uint4 v = *(const uint4*)(wb + o*4);
          accw ^= v.x ^ v.y ^ v.z ^ v.w;
        }
        asm volatile("" :: "v"(accw));
      }
      if (tid == 0) d_poll(bars, iBb, 64);
      __syncthreads();
    } else {
      // ---- dec-attention (phase 1, after mini-barrier M) ----
      int col = tid*4;
      if (i == 0){
        u16x4 z4v = {0,0,0,0};
        *(u16x4*)(xbuf + (size_t)db*1024 + col) = z4v;
        *(u16x4*)(Av + ((size_t)db*TD_ + i)*3072 + 2048 + col) = z4v;
      } else {
        if (tid == 0) d_poll(bars, iM, 64);
        __syncthreads();
        const unsigned short* hq = hreg + p*16384 + db*H2_ + l*16;
        u16x8 h0v = *(const u16x8*)hq;
        u16x8 h1v = *(const u16x8*)(hq + 8);
        float qf[16];
        #pragma unroll
        for (int c = 0; c < 8; ++c){ qf[c] = bf2f(h0v[c]); qf[8+c] = bf2f(h1v[c]); }
        for (int tp = wv; tp < i; tp += 4){
          const unsigned short* vr = vbuf + ((size_t)tp*16 + db)*H2_ + l*16;
          u16x8 e0 = *(const u16x8*)vr;
          u16x8 e1 = *(const u16x8*)(vr + 8);
          float sc = 0.f;
          #pragma unroll
          for (int c = 0; c < 8; ++c) sc += qf[c]*bf2f(e0[c]);
          #pragma unroll
          for (int c = 0; c < 8; ++c) sc += qf[8+c]*bf2f(e1[c]);
          #pragma unroll
          for (int o = 1; o < 64; o <<= 1) sc += __shfl_xor(sc, o);
          if (l == 0) dscL[tp] = sc;
        }
        __syncthreads();
        float scv = (l < i) ? dscL[l] : -1e30f;
        float m = scv;
        #pragma unroll
        for (int o = 1; o < 64; o <<= 1) m = fmaxf(m, __shfl_xor(m, o));
        float e = (l < i) ? expf(scv - m) : 0.f;
        float ssum = e;
        #pragma unroll
        for (int o = 1; o < 64; o <<= 1) ssum += __shfl_xor(ssum, o);
        float wgt = e / ssum;
        float c0_=0.f,c1_=0.f,c2_=0.f,c3_=0.f;
        for (int tp = 0; tp < i; ++tp){
          float wt = __shfl(wgt, tp);
          u16x4 hv = *(const u16x4*)(bufh + ((size_t)tp*16 + db)*H2_ + col);
          c0_ += wt*bf2f(hv[0]); c1_ += wt*bf2f(hv[1]); c2_ += wt*bf2f(hv[2]); c3_ += wt*bf2f(hv[3]);
        }
        u16x4 o4; o4[0]=f2bf(c0_); o4[1]=f2bf(c1_); o4[2]=f2bf(c2_); o4[3]=f2bf(c3_);
        *(u16x4*)(xbuf + (size_t)db*1024 + col) = o4;
        *(u16x4*)(Av + ((size_t)db*TD_ + i)*3072 + 2048 + col) = o4;
      }
      __syncthreads();
      if (tid == 0){ d_arrive(bars, iAb); d_poll(bars, iBb, 64); }
      __syncthreads();
    }
  }
}

// ---------------- vocab GEMM ----------------
__global__ void __launch_bounds__(256, 2) k_vocab_gemm(
    const unsigned short* __restrict__ Av,
    const float* __restrict__ Wv,
    const float* __restrict__ bv,
    float* __restrict__ out)
{
  __shared__ unsigned short Ab[128*72];
  __shared__ unsigned short Bt[128*72];
  int p = blockIdx.x;
  int mt = (p>>3)&7, nt = (p&7) + 8*(p>>6);
  if (nt >= 250) return;
  int m0 = mt*128, n0 = nt*128;
  int tid = threadIdx.x, wvv = tid>>6, l = tid&63;
  int wr = wvv>>1, wc = wvv&1;
  f32x4 zero4 = {0.f,0.f,0.f,0.f};
  f32x4 acc[4][4];
  #pragma unroll
  for (int a=0;a<4;++a){
    #pragma unroll
    for (int b=0;b<4;++b) acc[a][b] = zero4;
  }
  for (int k0 = 0; k0 < 3072; k0 += 64){
    #pragma unroll
    for (int qq = 0; qq < 4; ++qq){
      int idx8 = (tid + qq*256)*8;
      int r = idx8 >> 6, k = idx8 & 63;
      *(u16x8*)(Ab + r*72 + k) = *(const u16x8*)(Av + (size_t)(m0+r)*3072 + k0 + k);
    }
    #pragma unroll
    for (int qq = 0; qq < 4; ++qq){
      int idx8 = (tid + qq*256)*8;
      int r = idx8 >> 6, k = idx8 & 63;
      const float* src = Wv + (size_t)(n0+r)*3072 + k0 + k;
      float4 v0 = *(const float4*)src;
      float4 v1 = *(const float4*)(src+4);
      u16x8 o;
      o[0]=f2bf(v0.x); o[1]=f2bf(v0.y); o[2]=f2bf(v0.z); o[3]=f2bf(v0.w);
      o[4]=f2bf(v1.x); o[5]=f2bf(v1.y); o[6]=f2bf(v1.z); o[7]=f2bf(v1.w);
      *(u16x8*)(Bt + r*72 + k) = o;
    }
    __syncthreads();
    #pragma unroll
    for (int ks = 0; ks < 2; ++ks){
      s16x8 af[4], bf[4];
      #pragma unroll
      for (int fi=0;fi<4;++fi)
        af[fi] = *(const s16x8*)(Ab + (wr*64+fi*16+(l&15))*72 + ks*32 + (l>>4)*8);
      #pragma unroll
      for (int fj=0;fj<4;++fj)
        bf[fj] = *(const s16x8*)(Bt + (wc*64+fj*16+(l&15))*72 + ks*32 + (l>>4)*8);
      #pragma unroll
      for (int fi=0;fi<4;++fi){
        #pragma unroll
        for (int fj=0;fj<4;++fj)
          acc[fi][fj] = __builtin_amdgcn_mfma_f32_16x16x32_bf16(af[fi], bf[fj], acc[fi][fj], 0,0,0);
      }
    }
    __syncthreads();
  }
  #pragma unroll
  for (int fj=0;fj<4;++fj){
    int col = n0 + wc*64 + fj*16 + (l&15);
    float bias = bv[col];
    #pragma unroll
    for (int fi=0;fi<4;++fi){
      #pragma unroll
      for (int j=0;j<4;++j){
        int row = m0 + wr*64 + fi*16 + (l>>4)*4 + j;
        out[(size_t)row*V_ + col] = acc[fi][fj][j] + bias;
      }
    }
  }
}

// ---------------- in-place log-softmax ----------------
__global__ void k_logsoftmax(float* __restrict__ out){
  int row = blockIdx.x;
  float* x = out + (size_t)row*V_;
  int tid = threadIdx.x;
  __shared__ float red[64];
  float m = -1e30f;
  for (int c = tid; c < V_; c += 256) m = fmaxf(m, x[c]);
  #pragma unroll
  for (int o=1;o<64;o<<=1) m = fmaxf(m, __shfl_xor(m,o));
  if ((tid&63)==0) red[tid>>6] = m;
  __syncthreads();
  m = fmaxf(fmaxf(red[0],red[1]), fmaxf(red[2],red[3]));
  float s = 0.f;
  for (int c = tid; c < V_; c += 256) s += expf(x[c]-m);
  #pragma unroll
  for (int o=1;o<64;o<<=1) s += __shfl_xor(s,o);
  if ((tid&63)==0) red[8 + (tid>>6)] = s;
  __syncthreads();
  s = red[8]+red[9]+red[10]+red[11];
  float lse = m + logf(s);
  for (int c = tid; c < V_; c += 256) x[c] = x[c] - lse;
}

extern "C" void kernel_launch(void* const* d_in, const int* in_sizes, int n_in,
                              void* d_out, int out_size, void* d_ws, size_t ws_size,
                              hipStream_t stream){
  (void)in_sizes; (void)n_in; (void)out_size; (void)ws_size;
  const int*   enc_in = (const int*)d_in[0];
  const int*   dec_in = (const int*)d_in[1];
  const float* h0   = (const float*)d_in[4];
  const float* c0   = (const float*)d_in[5];
  const float* emb  = (const float*)d_in[6];
  const float* Wih_f= (const float*)d_in[7];
  const float* Whh_f= (const float*)d_in[8];
  const float* b_f  = (const float*)d_in[9];
  const float* Wih_b= (const float*)d_in[10];
  const float* Whh_b= (const float*)d_in[11];
  const float* b_b  = (const float*)d_in[12];
  const float* Wih_d= (const float*)d_in[13];
  const float* Whh_d= (const float*)d_in[14];
  const float* b_d  = (const float*)d_in[15];
  const float* W_ea = (const float*)d_in[16];
  const float* W_da = (const float*)d_in[17];
  const float* W_v  = (const float*)d_in[18];
  const float* b_v  = (const float*)d_in[19];
  float* out = (float*)d_out;
  char* ws = (char*)d_ws;

  size_t o_bars   = 0;                              // 99328 u32 = 397312 B
  size_t o_ctxn   = 397312;                         // [2][16][1024] f32
  size_t o_psumT  = o_ctxn + 131072;
  size_t o_xs     = o_psumT + 256;
  size_t o_decemb = o_xs + (size_t)6400*256*2;
  size_t o_Wenc   = o_decemb + (size_t)1024*256*2;
  size_t o_WhExt  = o_Wenc + (size_t)2*2048*768*2;
  size_t o_CtxW   = o_WhExt + (size_t)64*163840;
  size_t o_Wemb   = o_CtxW + (size_t)64*262144;
  size_t o_zinit  = o_Wemb + (size_t)4096*256*2;
  size_t o_zx     = o_zinit + (size_t)1024*4096*4;
  size_t o_enc    = o_zx + (size_t)2*6400*2048*2;
  size_t o_Penc   = o_enc + (size_t)16*400*1024*2;
  size_t o_hbuf   = o_Penc + (size_t)16*400*1024*2;
  size_t o_h0dec  = o_hbuf + (size_t)2*2*16*512*2;
  size_t o_c0dec  = o_h0dec + (size_t)16*1024*4;
  size_t o_hreg   = o_c0dec + (size_t)16*1024*4;
  size_t o_xbuf   = o_hreg + (size_t)2*16*1024*2;
  size_t o_vbuf   = o_xbuf + (size_t)16*1024*2;
  size_t o_bufh   = o_vbuf + (size_t)64*16*1024*2;
  size_t o_Av     = o_bufh + (size_t)64*16*1024*2;

  unsigned* bars        = (unsigned*)(ws + o_bars);
  float* ctxn           = (float*)(ws + o_ctxn);
  float* psumT          = (float*)(ws + o_psumT);
  unsigned short* xs    = (unsigned short*)(ws + o_xs);
  unsigned short* decemb= (unsigned short*)(ws + o_decemb);
  unsigned short* Wenc  = (unsigned short*)(ws + o_Wenc);
  char* WhExt           = ws + o_WhExt;
  char* CtxW            = ws + o_CtxW;
  unsigned short* Wemb  = (unsigned short*)(ws + o_Wemb);
  float* zinit          = (float*)(ws + o_zinit);
  unsigned short* zx    = (unsigned short*)(ws + o_zx);
  unsigned short* encO  = (unsigned short*)(ws + o_enc);
  unsigned short* Penc  = (unsigned short*)(ws + o_Penc);
  unsigned short* hbuf  = (unsigned short*)(ws + o_hbuf);
  float* h0dec          = (float*)(ws + o_h0dec);
  float* c0dec          = (float*)(ws + o_c0dec);
  unsigned short* hreg  = (unsigned short*)(ws + o_hreg);
  unsigned short* xbuf  = (unsigned short*)(ws + o_xbuf);
  unsigned short* vbuf  = (unsigned short*)(ws + o_vbuf);
  unsigned short* bufh  = (unsigned short*)(ws + o_bufh);
  unsigned short* Av    = (unsigned short*)(ws + o_Av);

  hipFuncSetAttribute((const void*)k_encoder, hipFuncAttributeMaxDynamicSharedMemorySize, 90000);
  hipFuncSetAttribute((const void*)k_decoder, hipFuncAttributeMaxDynamicSharedMemorySize, 160768);

  k_init<<<392, 256, 0, stream>>>(bars, ctxn, psumT);
  k_gather<<<1600, 256, 0, stream>>>(emb, enc_in, xs, TE_);
  k_gather<<<256, 256, 0, stream>>>(emb, dec_in, decemb, TD_);
  k_prep_enc<<<1536, 256, 0, stream>>>(Wih_f, Whh_f, Wih_b, Whh_b, Wenc);
  k_prep_wihemb<<<512, 256, 0, stream>>>(Wih_d, Wemb);
  k_zinit<<<256, 256, 0, stream>>>(decemb, Wemb, b_d, zinit);
  k_zx<<<1600, 256, 0, stream>>>(xs, Wenc, b_f, b_b, zx);
  k_encoder<<<208, 256, 87296, stream>>>(zx, Wenc, h0, c0, encO, hbuf, h0dec, c0dec, bars,
                                         Whh_d, W_da, Wih_d, WhExt, CtxW);
  k_penc<<<400, 256, 0, stream>>>(encO, W_ea, Penc);
  k_dec_init<<<64, 256, 0, stream>>>(h0dec, hreg);
  k_decoder<<<208, 256, 160768, stream>>>(WhExt, CtxW, zinit, Penc, encO, c0dec,
                                          hreg, xbuf, ctxn, psumT, vbuf, bufh, Av,
                                          out + (size_t)32768000, bars);
  k_vocab_gemm<<<2048, 256, 0, stream>>>(Av, W_v, b_v, out);
  k_logsoftmax<<<1024, 256, 0, stream>>>(out);
}